// Round 5
// baseline (572.335 us; speedup 1.0000x reference)
//
#include <hip/hip_runtime.h>
#include <hip/hip_fp16.h>
#include <math.h>

// Problem constants (match reference)
static constexpr int ND  = 150000;   // total nodes
static constexpr int NUU = 100000;   // num users
static constexpr int BB  = 16384;    // batch
static constexpr int EE  = 2000000;  // edges (before self loops)
static constexpr int ETOT = EE + ND; // edges incl self loops

// bucket sort params
static constexpr int NBUK  = (ND + 127) >> 7;          // 1172 buckets of 128 nodes
static constexpr int CAP   = 4096;                     // per-bucket capacity (avg ~1835)
static constexpr int CHUNK = 8192;
static constexpr int NCH   = (ETOT + CHUNK - 1) / CHUNK;

typedef _Float16 h8 __attribute__((ext_vector_type(8)));
typedef float    f4 __attribute__((ext_vector_type(4)));

// ---------------- wave helpers ----------------
__device__ __forceinline__ float wsum64(float v){
#pragma unroll
  for (int d = 32; d > 0; d >>= 1) v += __shfl_xor(v, d, 64);
  return v;
}

// ---------------- weight prep ----------------
__global__ __launch_bounds__(256) void k_conv(const float* __restrict__ w1,
    const float* __restrict__ w2, __half* __restrict__ Wt1, __half* __restrict__ Wt2){
  int t = blockIdx.x * 256 + threadIdx.x;
  if (t < 16384) {
    int n = t >> 7, k = t & 127;
    Wt1[t] = __float2half(w1[k * 128 + n]);
  } else if (t < 24576) {
    int u = t - 16384;
    int n = u >> 7, k = u & 127;
    Wt2[u] = __float2half(w2[k * 64 + n]);
  }
}

// wa = W @ a^T
__global__ __launch_bounds__(128) void k_wa(const float* __restrict__ w1,
    const float* __restrict__ asrc1, const float* __restrict__ adst1,
    const float* __restrict__ w2, const float* __restrict__ asrc2,
    const float* __restrict__ adst2,
    float* __restrict__ wa1s, float* __restrict__ wa1d,
    float* __restrict__ wa2s, float* __restrict__ wa2d){
  int k = threadIdx.x;  // 0..127
  float s0 = 0.f, s1 = 0.f, d0 = 0.f, d1 = 0.f, s2 = 0.f, d2 = 0.f;
  for (int c = 0; c < 64; c++) {
    float wA = w1[k * 128 + c];
    float wB = w1[k * 128 + 64 + c];
    s0 = fmaf(wA, asrc1[c], s0);       d0 = fmaf(wA, adst1[c], d0);
    s1 = fmaf(wB, asrc1[64 + c], s1);  d1 = fmaf(wB, adst1[64 + c], d1);
    float wC = w2[k * 64 + c];
    s2 = fmaf(wC, asrc2[c], s2);       d2 = fmaf(wC, adst2[c], d2);
  }
  wa1s[k * 2] = s0; wa1s[k * 2 + 1] = s1;
  wa1d[k * 2] = d0; wa1d[k * 2 + 1] = d1;
  wa2s[k] = s2; wa2d[k] = d2;
}

// ---------------- input scatter (fp16 x) + fused layer-1 scores ----------------
__global__ __launch_bounds__(256) void k_users(const int* __restrict__ uids,
    const float* __restrict__ uemb, __half* __restrict__ x,
    const float* __restrict__ wa1s, const float* __restrict__ wa1d,
    float* __restrict__ als1, float* __restrict__ ald1){
  int t = blockIdx.x * 256 + threadIdx.x;
  int b = t >> 6, c = t & 63;          // one wave per row
  int uid = uids[b];
  float u = uemb[(size_t)uid * 64 + c];
  x[(size_t)uid * 128 + c] = __float2half(u);
  float2 ws = *(const float2*)(wa1s + 2 * c);
  float2 wd = *(const float2*)(wa1d + 2 * c);
  float s0 = wsum64(u * ws.x);
  float s1 = wsum64(u * ws.y);
  float d0 = wsum64(u * wd.x);
  float d1 = wsum64(u * wd.y);
  if (c == 0) {
    *(float2*)(als1 + (size_t)uid * 2) = make_float2(s0, s1);
    *(float2*)(ald1 + (size_t)uid * 2) = make_float2(d0, d1);
  }
}

__global__ __launch_bounds__(256) void k_items(const float* __restrict__ content,
    const float* __restrict__ cpw, const float* __restrict__ cpb,
    const float* __restrict__ iemb, const int* __restrict__ iids,
    __half* __restrict__ x,
    const float* __restrict__ wa1s, const float* __restrict__ wa1d,
    float* __restrict__ als1, float* __restrict__ ald1){
  int c  = threadIdx.x & 63;
  int rr = threadIdx.x >> 6;
  int r0 = blockIdx.x * 16 + rr * 4;
  float acc[4] = {0.f, 0.f, 0.f, 0.f};
  for (int k = 0; k < 256; k++) {
    float wv = cpw[k * 64 + c];
#pragma unroll
    for (int i = 0; i < 4; i++)
      acc[i] = fmaf(content[(size_t)(r0 + i) * 256 + k], wv, acc[i]);
  }
  float2 wsL = *(const float2*)(wa1s + 2 * c);
  float2 wdL = *(const float2*)(wa1d + 2 * c);
  float2 wsH = *(const float2*)(wa1s + 128 + 2 * c);
  float2 wdH = *(const float2*)(wa1d + 128 + 2 * c);
#pragma unroll
  for (int i = 0; i < 4; i++) {
    int r = r0 + i;
    if (r >= BB) continue;
    int iid = iids[r];
    size_t node = (size_t)(NUU + iid);
    float hi = acc[i] + cpb[c];
    float lo = iemb[(size_t)iid * 64 + c];
    x[node * 128 + 64 + c] = __float2half(hi);
    x[node * 128 + c]      = __float2half(lo);
    float s0 = wsum64(lo * wsL.x + hi * wsH.x);
    float s1 = wsum64(lo * wsL.y + hi * wsH.y);
    float d0 = wsum64(lo * wdL.x + hi * wdH.x);
    float d1 = wsum64(lo * wdL.y + hi * wdH.y);
    if (c == 0) {
      *(float2*)(als1 + node * 2) = make_float2(s0, s1);
      *(float2*)(ald1 + node * 2) = make_float2(d0, d1);
    }
  }
}

// ---------------- CSR build via bucket sort ----------------
__global__ __launch_bounds__(256) void k_bin(const int* __restrict__ ei,
    int* __restrict__ bucket_cnt, int2* __restrict__ bucket_data){
  __shared__ int hist[NBUK];
  __shared__ int base[NBUK];
  int tid = threadIdx.x;
  int t0 = blockIdx.x * CHUNK;
  for (int i = tid; i < NBUK; i += 256) hist[i] = 0;
  __syncthreads();
  for (int i = tid; i < CHUNK; i += 256) {
    int t = t0 + i;
    if (t >= ETOT) break;
    int dst = (t < EE) ? ei[EE + t] : (t - EE);
    atomicAdd(&hist[dst >> 7], 1);
  }
  __syncthreads();
  for (int b = tid; b < NBUK; b += 256) {
    int c = hist[b];
    base[b] = c ? atomicAdd(&bucket_cnt[b], c) : 0;
    hist[b] = 0;
  }
  __syncthreads();
  for (int i = tid; i < CHUNK; i += 256) {
    int t = t0 + i;
    if (t >= ETOT) break;
    int src, dst;
    if (t < EE) { src = ei[t]; dst = ei[EE + t]; }
    else        { src = dst = t - EE; }
    int b = dst >> 7;
    int r = base[b] + atomicAdd(&hist[b], 1);
    if (r < CAP) bucket_data[(size_t)b * CAP + r] = make_int2(src, dst);
  }
}

__global__ void k_bscan(const int* __restrict__ cnt, int* __restrict__ bbase,
                        int* __restrict__ offs_end){
  int lane = threadIdx.x;   // 64 threads
  int carry = 0;
  for (int c0 = 0; c0 < NBUK; c0 += 64) {
    int i = c0 + lane;
    int v = (i < NBUK) ? cnt[i] : 0;
    int x = v;
#pragma unroll
    for (int d = 1; d < 64; d <<= 1) { int t = __shfl_up(x, d, 64); if (lane >= d) x += t; }
    if (i < NBUK) bbase[i] = carry + x - v;
    carry += __shfl(x, 63, 64);
  }
  if (lane == 0) *offs_end = carry;   // offs[ND] = ETOT
}

__global__ __launch_bounds__(256) void k_bucket(const int2* __restrict__ bucket_data,
    const int* __restrict__ bucket_cnt, const int* __restrict__ bbase,
    int* __restrict__ offs, int* __restrict__ csr){
  __shared__ int degL[128];
  __shared__ int curL[128];
  int b = blockIdx.x;
  int tid = threadIdx.x;
  int cnt = bucket_cnt[b];
  int base = bbase[b];
  if (tid < 128) degL[tid] = 0;
  __syncthreads();
  const int2* bd = bucket_data + (size_t)b * CAP;
  for (int i = tid; i < cnt; i += 256)
    atomicAdd(&degL[bd[i].y & 127], 1);
  __syncthreads();
  if (tid < 64) {   // wave 0: exclusive scan of 128 degs
    int v0 = degL[tid], v1 = degL[64 + tid];
    int s0 = v0, s1 = v1;
#pragma unroll
    for (int d = 1; d < 64; d <<= 1) {
      int t0 = __shfl_up(s0, d, 64); if (tid >= d) s0 += t0;
      int t1 = __shfl_up(s1, d, 64); if (tid >= d) s1 += t1;
    }
    int tot0 = __shfl(s0, 63, 64);
    int e0 = s0 - v0;
    int e1 = s1 - v1 + tot0;
    curL[tid] = e0; curL[64 + tid] = e1;
    int g0 = b * 128 + tid, g1 = b * 128 + 64 + tid;
    if (g0 < ND) offs[g0] = base + e0;
    if (g1 < ND) offs[g1] = base + e1;
  }
  __syncthreads();
  for (int i = tid; i < cnt; i += 256) {
    int2 e = bd[i];
    int p = atomicAdd(&curL[e.y & 127], 1);
    csr[base + p] = e.x;
  }
}

// ---------------- MFMA fp16 GEMM: C[M,N](f16) = A[M,128](f16) @ Bt[N,128]^T ----------------
template<int NT>   // N = NT*16
__global__ __launch_bounds__(256) void k_mfma(const __half* __restrict__ A,
    const __half* __restrict__ Bt, __half* __restrict__ C, int M){
  constexpr int N = NT * 16;
  int wid  = (blockIdx.x * 256 + threadIdx.x) >> 6;
  int lane = threadIdx.x & 63;
  int q = lane >> 4, mr = lane & 15;
  int r0 = wid * 32;
  if (r0 >= M) return;
  int row0 = min(r0 + mr, M - 1);
  int row1 = min(r0 + 16 + mr, M - 1);
  f4 acc[2][NT];
#pragma unroll
  for (int i = 0; i < 2; i++)
#pragma unroll
    for (int j = 0; j < NT; j++) acc[i][j] = (f4)0.f;
#pragma unroll
  for (int ks = 0; ks < 4; ks++) {
    int ko = ks * 32 + q * 8;
    h8 a0 = *(const h8*)(A + (size_t)row0 * 128 + ko);
    h8 a1 = *(const h8*)(A + (size_t)row1 * 128 + ko);
#pragma unroll
    for (int nt = 0; nt < NT; nt++) {
      h8 b = *(const h8*)(Bt + (size_t)(nt * 16 + mr) * 128 + ko);
      acc[0][nt] = __builtin_amdgcn_mfma_f32_16x16x32_f16(a0, b, acc[0][nt], 0, 0, 0);
      acc[1][nt] = __builtin_amdgcn_mfma_f32_16x16x32_f16(a1, b, acc[1][nt], 0, 0, 0);
    }
  }
#pragma unroll
  for (int mt = 0; mt < 2; mt++)
#pragma unroll
    for (int r = 0; r < 4; r++) {
      int row = r0 + mt * 16 + q * 4 + r;
      if (row < M) {
#pragma unroll
        for (int nt = 0; nt < NT; nt++)
          C[(size_t)row * N + nt * 16 + mr] = __float2half(acc[mt][nt][r]);
      }
    }
}

// ---------------- GAT aggregation, H=2 (layer 1) ----------------
// one wave per dst. Per edge: scalar s_load of src, LDS-broadcast p, 1 coalesced
// 256B row load, 2 FMA. No per-edge shuffles.
__global__ __launch_bounds__(256) void k_agg2(const __half2* __restrict__ xw,
    const float* __restrict__ als, const float* __restrict__ ald,
    const int* __restrict__ offs, const int* __restrict__ csr,
    const float* __restrict__ bias, __half* __restrict__ out,
    const float* __restrict__ wa2s, const float* __restrict__ wa2d,
    float* __restrict__ als2, float* __restrict__ ald2, int n){
  __shared__ float pshare[4][2][64];
  int gw = (blockIdx.x * 256 + threadIdx.x) >> 6;
  int lane = threadIdx.x & 63;
  int ws = (threadIdx.x >> 6) & 3;
  if (gw >= n) return;
  int e0 = __builtin_amdgcn_readfirstlane(offs[gw]);
  int e1 = __builtin_amdgcn_readfirstlane(offs[gw + 1]);
  float2 aldv = *(const float2*)(ald + (size_t)gw * 2);
  bool lo = lane < 32;
  const float* myp = &pshare[ws][0][0] + (lo ? 0 : 64);
  float den0 = 0.f, den1 = 0.f, accx = 0.f, accy = 0.f;
  for (int base = e0; base < e1; base += 64) {
    int e = base + lane;
    bool valid = (e < e1);
    int srcv = valid ? csr[e] : 0;
    float p0 = 0.f, p1 = 0.f;
    if (valid) {
      float2 a = *(const float2*)(als + (size_t)srcv * 2);
      float v0 = a.x + aldv.x, v1 = a.y + aldv.y;
      v0 = fmaxf(v0, 0.2f * v0);
      v1 = fmaxf(v1, 0.2f * v1);
      p0 = __expf(v0); p1 = __expf(v1);
    }
    den0 += p0; den1 += p1;                  // per-lane partials; reduced once at end
    pshare[ws][0][lane] = p0;
    pshare[ws][1][lane] = p1;                // same-wave DS ordering: write before read
    int cnt = min(e1 - base, 64);
    const int* cp = csr + base;              // wave-uniform -> s_load
    int j = 0;
    for (; j + 8 <= cnt; j += 8) {
      __half2 hv[8]; float pj[8];
#pragma unroll
      for (int u = 0; u < 8; u++) {
        int sj = __builtin_amdgcn_readfirstlane(cp[j + u]);
        hv[u] = xw[(size_t)sj * 64 + lane];  // SGPR base + lane offset
        pj[u] = myp[j + u];                  // ds_read broadcast
      }
#pragma unroll
      for (int u = 0; u < 8; u++) {
        float2 fv = __half22float2(hv[u]);
        accx = fmaf(pj[u], fv.x, accx);
        accy = fmaf(pj[u], fv.y, accy);
      }
    }
    for (; j < cnt; j++) {
      int sj = __builtin_amdgcn_readfirstlane(cp[j]);
      __half2 hv = xw[(size_t)sj * 64 + lane];
      float pj = myp[j];
      float2 fv = __half22float2(hv);
      accx = fmaf(pj, fv.x, accx);
      accy = fmaf(pj, fv.y, accy);
    }
  }
  float dt0 = wsum64(den0), dt1 = wsum64(den1);
  float den = (lo ? dt0 : dt1) + 1e-16f;
  float inv = 1.f / den;
  float2 b = *(const float2*)(bias + 2 * lane);
  float vx = accx * inv + b.x;
  float vy = accy * inv + b.y;
  vx = (vx > 0.f) ? vx : expm1f(vx);         // elu
  vy = (vy > 0.f) ? vy : expm1f(vy);
  *(__half2*)(out + (size_t)gw * 128 + 2 * lane) = __floats2half2_rn(vx, vy);
  float2 wsv = *(const float2*)(wa2s + 2 * lane);
  float2 wdv = *(const float2*)(wa2d + 2 * lane);
  float s_s = wsum64(vx * wsv.x + vy * wsv.y);
  float s_d = wsum64(vx * wdv.x + vy * wdv.y);
  if (lane == 0) { als2[gw] = s_s; ald2[gw] = s_d; }
}

// ---------------- GAT aggregation, H=1 (layer 2): 2 edges per instruction ----------------
__global__ __launch_bounds__(256) void k_agg1(const __half2* __restrict__ xw,
    const float* __restrict__ als, const float* __restrict__ ald,
    const int* __restrict__ offs, const int* __restrict__ csr,
    const float* __restrict__ bias, __half* __restrict__ out, int n){
  __shared__ float pshare[4][64];
  int gw = (blockIdx.x * 256 + threadIdx.x) >> 6;
  int lane = threadIdx.x & 63;
  int ws = (threadIdx.x >> 6) & 3;
  if (gw >= n) return;
  int e0 = __builtin_amdgcn_readfirstlane(offs[gw]);
  int e1 = __builtin_amdgcn_readfirstlane(offs[gw + 1]);
  float aldd = ald[gw];
  int hid = lane >> 5;
  int c = lane & 31;
  const float* myp = &pshare[ws][0] + hid;   // lanes<32 read p[j], >=32 read p[j+1]
  float den = 0.f, accx = 0.f, accy = 0.f;
  for (int base = e0; base < e1; base += 64) {
    int e = base + lane;
    bool valid = (e < e1);
    int srcv = valid ? csr[e] : 0;
    float p = 0.f;
    if (valid) {
      float v = als[srcv] + aldd;
      v = fmaxf(v, 0.2f * v);
      p = __expf(v);
    }
    den += p;
    pshare[ws][lane] = p;
    int cnt = min(e1 - base, 64);
    const int* cp = csr + base;
    for (int j = 0; j < cnt; j += 2) {
      int sj0 = __builtin_amdgcn_readfirstlane(cp[j]);
      int sj1 = __builtin_amdgcn_readfirstlane(cp[min(j + 1, cnt - 1)]);
      int sel = hid ? sj1 : sj0;             // 1 cndmask from 2 SGPRs
      __half2 hv = xw[(size_t)sel * 32 + c];
      float pj = myp[j];                     // ds_read broadcast (2 addrs/wave)
      float2 fv = __half22float2(hv);
      accx = fmaf(pj, fv.x, accx);
      accy = fmaf(pj, fv.y, accy);
    }
  }
  accx += __shfl_xor(accx, 32, 64);
  accy += __shfl_xor(accy, 32, 64);
  float dent = wsum64(den);
  if (lane < 32) {
    float inv = 1.f / (dent + 1e-16f);
    float2 b = *(const float2*)(bias + 2 * c);
    float vx = accx * inv + b.x;
    float vy = accy * inv + b.y;
    *(__half2*)(out + (size_t)gw * 64 + 2 * c) = __floats2half2_rn(vx, vy);
  }
}

// ---------------- prediction head: 16 rows/block, LDS weight reuse ----------------
__global__ __launch_bounds__(256) void k_head(const float* __restrict__ uemb,
    const int* __restrict__ uids, const int* __restrict__ iids,
    const __half* __restrict__ x2, const float* __restrict__ pw1,
    const float* __restrict__ pb1, const float* __restrict__ pw2,
    const float* __restrict__ pb2, float* __restrict__ out, int B){
  __shared__ __align__(16) float pw1_s[192 * 64];  // 48KB
  __shared__ float comb_s[16][192];
  for (int i = threadIdx.x; i < 192 * 64 / 4; i += 256)
    ((float4*)pw1_s)[i] = ((const float4*)pw1)[i];
  int w = threadIdx.x >> 6, lane = threadIdx.x & 63;
#pragma unroll
  for (int rr = 0; rr < 4; rr++) {
    int r = w * 4 + rr;
    int b = blockIdx.x * 16 + r;
    if (b < B) {
      int uid = uids[b], iid = iids[b];
      comb_s[r][lane]       = uemb[(size_t)uid * 64 + lane];
      comb_s[r][64 + lane]  = __half2float(x2[(size_t)(NUU + iid) * 64 + lane]);
      comb_s[r][128 + lane] = __half2float(x2[(size_t)uid * 64 + lane]);
    }
  }
  __syncthreads();
  float pw2v = pw2[lane];
  float pb1v = pb1[lane];
#pragma unroll
  for (int rr = 0; rr < 4; rr++) {
    int r = w * 4 + rr;
    int b = blockIdx.x * 16 + r;
    if (b >= B) continue;
    float acc = pb1v;
#pragma unroll 8
    for (int j = 0; j < 192; j++)
      acc = fmaf(comb_s[r][j], pw1_s[j * 64 + lane], acc);
    acc = fmaxf(acc, 0.f);
    float prod = wsum64(acc * pw2v);
    if (lane == 0) out[b] = prod + pb2[0];
  }
}

// ---------------- launcher ----------------
extern "C" void kernel_launch(void* const* d_in, const int* in_sizes, int n_in,
                              void* d_out, int out_size, void* d_ws, size_t ws_size,
                              hipStream_t stream) {
  (void)in_sizes; (void)n_in; (void)out_size; (void)ws_size;
  const int*   user_ids = (const int*)  d_in[0];
  const int*   item_ids = (const int*)  d_in[1];
  const float* content  = (const float*)d_in[2];
  const int*   edge_idx = (const int*)  d_in[3];
  const float* uemb     = (const float*)d_in[4];
  const float* iemb     = (const float*)d_in[5];
  const float* cp_w     = (const float*)d_in[6];
  const float* cp_b     = (const float*)d_in[7];
  const float* w1       = (const float*)d_in[8];
  const float* asrc1    = (const float*)d_in[9];
  const float* adst1    = (const float*)d_in[10];
  const float* b1       = (const float*)d_in[11];
  const float* w2       = (const float*)d_in[12];
  const float* asrc2    = (const float*)d_in[13];
  const float* adst2    = (const float*)d_in[14];
  const float* b2       = (const float*)d_in[15];
  const float* pw1      = (const float*)d_in[16];
  const float* pb1      = (const float*)d_in[17];
  const float* pw2      = (const float*)d_in[18];
  const float* pb2      = (const float*)d_in[19];
  float* out = (float*)d_out;

  // workspace layout (~128 MB)
  __half* x    = (__half*)d_ws;                        // [ND,128] f16; reused as x1
  __half* xw   = x + (size_t)ND * 128;                 // [ND,128] f16 xw1; L2: xw2 + out2
  float* als1  = (float*)(xw + (size_t)ND * 128);      // [ND,2]
  float* ald1  = als1 + (size_t)ND * 2;                // [ND,2]
  float* als2  = ald1 + (size_t)ND * 2;                // [ND]
  float* ald2  = als2 + ND;                            // [ND]
  int* offs    = (int*)(ald2 + ND);                    // [ND+4]
  int* bcnt    = offs + ND + 4;                        // [NBUK]
  int* bbase   = bcnt + NBUK;                          // [NBUK]
  int* csr     = bbase + NBUK;                         // [ETOT+2]
  int2* bdata  = (int2*)(csr + ETOT + 2);              // [NBUK*CAP] 8B-aligned
  __half* Wt1  = (__half*)(bdata + (size_t)NBUK * CAP); // [128,128]
  __half* Wt2  = Wt1 + 16384;                          // [64,128]
  float* wa1s  = (float*)(Wt2 + 8192);                 // [128,2]
  float* wa1d  = wa1s + 256;                           // [128,2]
  float* wa2s  = wa1d + 256;                           // [128]
  float* wa2d  = wa2s + 128;                           // [128]
  __half* xw2  = xw;                                   // [ND,64]
  __half* out2 = xw + (size_t)ND * 64;                 // [ND,64]

  hipMemsetAsync(x, 0, (size_t)ND * 128 * sizeof(__half), stream);
  hipMemsetAsync(als1, 0, (size_t)ND * 4 * sizeof(float), stream);  // als1+ald1
  hipMemsetAsync(bcnt, 0, NBUK * sizeof(int), stream);

  k_conv<<<96, 256, 0, stream>>>(w1, w2, Wt1, Wt2);
  k_wa<<<1, 128, 0, stream>>>(w1, asrc1, adst1, w2, asrc2, adst2, wa1s, wa1d, wa2s, wa2d);

  k_users<<<BB * 64 / 256, 256, 0, stream>>>(user_ids, uemb, x, wa1s, wa1d, als1, ald1);
  k_items<<<BB / 16, 256, 0, stream>>>(content, cp_w, cp_b, iemb, item_ids, x,
                                       wa1s, wa1d, als1, ald1);

  // CSR build: bucket sort
  k_bin<<<NCH, 256, 0, stream>>>(edge_idx, bcnt, bdata);
  k_bscan<<<1, 64, 0, stream>>>(bcnt, bbase, offs + ND);
  k_bucket<<<NBUK, 256, 0, stream>>>(bdata, bcnt, bbase, offs, csr);

  // ----- GAT layer 1 (H=2) -----
  k_mfma<8><<<(ND + 127) / 128, 256, 0, stream>>>(x, Wt1, xw, ND);
  k_agg2<<<(ND * 64 + 255) / 256, 256, 0, stream>>>((const __half2*)xw, als1, ald1,
                                                    offs, csr, b1, x,
                                                    wa2s, wa2d, als2, ald2, ND);

  // ----- GAT layer 2 (H=1) -----
  k_mfma<4><<<(ND + 127) / 128, 256, 0, stream>>>(x, Wt2, xw2, ND);
  k_agg1<<<(ND * 64 + 255) / 256, 256, 0, stream>>>((const __half2*)xw2, als2, ald2,
                                                    offs, csr, b2, out2, ND);

  // ----- head -----
  k_head<<<(BB + 15) / 16, 256, 0, stream>>>(uemb, user_ids, item_ids, out2,
                                             pw1, pb1, pw2, pb2, out, BB);
}

// Round 6
// 526.928 us; speedup vs baseline: 1.0862x; 1.0862x over previous
//
#include <hip/hip_runtime.h>
#include <hip/hip_fp16.h>
#include <math.h>

// Problem constants (match reference)
static constexpr int ND  = 150000;   // total nodes
static constexpr int NUU = 100000;   // num users
static constexpr int BB  = 16384;    // batch
static constexpr int EE  = 2000000;  // edges (before self loops)
static constexpr int ETOT = EE + ND; // edges incl self loops

// bucket sort params
static constexpr int NBUK  = (ND + 127) >> 7;          // 1172 buckets of 128 nodes
static constexpr int CAP   = 4096;                     // per-bucket capacity (avg ~1835)
static constexpr int CHUNK = 8192;
static constexpr int NCH   = (ETOT + CHUNK - 1) / CHUNK;

typedef _Float16 h8 __attribute__((ext_vector_type(8)));
typedef float    f4 __attribute__((ext_vector_type(4)));

// ---------------- wave helpers ----------------
__device__ __forceinline__ float wsum64(float v){
#pragma unroll
  for (int d = 32; d > 0; d >>= 1) v += __shfl_xor(v, d, 64);
  return v;
}

// ---------------- weight prep ----------------
__global__ __launch_bounds__(256) void k_conv(const float* __restrict__ w1,
    const float* __restrict__ w2, __half* __restrict__ Wt1, __half* __restrict__ Wt2){
  int t = blockIdx.x * 256 + threadIdx.x;
  if (t < 16384) {
    int n = t >> 7, k = t & 127;
    Wt1[t] = __float2half(w1[k * 128 + n]);
  } else if (t < 24576) {
    int u = t - 16384;
    int n = u >> 7, k = u & 127;
    Wt2[u] = __float2half(w2[k * 64 + n]);
  }
}

// wa = W @ a^T
__global__ __launch_bounds__(128) void k_wa(const float* __restrict__ w1,
    const float* __restrict__ asrc1, const float* __restrict__ adst1,
    const float* __restrict__ w2, const float* __restrict__ asrc2,
    const float* __restrict__ adst2,
    float* __restrict__ wa1s, float* __restrict__ wa1d,
    float* __restrict__ wa2s, float* __restrict__ wa2d){
  int k = threadIdx.x;  // 0..127
  float s0 = 0.f, s1 = 0.f, d0 = 0.f, d1 = 0.f, s2 = 0.f, d2 = 0.f;
  for (int c = 0; c < 64; c++) {
    float wA = w1[k * 128 + c];
    float wB = w1[k * 128 + 64 + c];
    s0 = fmaf(wA, asrc1[c], s0);       d0 = fmaf(wA, adst1[c], d0);
    s1 = fmaf(wB, asrc1[64 + c], s1);  d1 = fmaf(wB, adst1[64 + c], d1);
    float wC = w2[k * 64 + c];
    s2 = fmaf(wC, asrc2[c], s2);       d2 = fmaf(wC, adst2[c], d2);
  }
  wa1s[k * 2] = s0; wa1s[k * 2 + 1] = s1;
  wa1d[k * 2] = d0; wa1d[k * 2 + 1] = d1;
  wa2s[k] = s2; wa2d[k] = d2;
}

// ---------------- input scatter (fp16 x) + fused layer-1 scores ----------------
__global__ __launch_bounds__(256) void k_users(const int* __restrict__ uids,
    const float* __restrict__ uemb, __half* __restrict__ x,
    const float* __restrict__ wa1s, const float* __restrict__ wa1d,
    float* __restrict__ als1, float* __restrict__ ald1){
  int t = blockIdx.x * 256 + threadIdx.x;
  int b = t >> 6, c = t & 63;          // one wave per row
  int uid = uids[b];
  float u = uemb[(size_t)uid * 64 + c];
  x[(size_t)uid * 128 + c] = __float2half(u);
  float2 ws = *(const float2*)(wa1s + 2 * c);
  float2 wd = *(const float2*)(wa1d + 2 * c);
  float s0 = wsum64(u * ws.x);
  float s1 = wsum64(u * ws.y);
  float d0 = wsum64(u * wd.x);
  float d1 = wsum64(u * wd.y);
  if (c == 0) {
    *(float2*)(als1 + (size_t)uid * 2) = make_float2(s0, s1);
    *(float2*)(ald1 + (size_t)uid * 2) = make_float2(d0, d1);
  }
}

__global__ __launch_bounds__(256) void k_items(const float* __restrict__ content,
    const float* __restrict__ cpw, const float* __restrict__ cpb,
    const float* __restrict__ iemb, const int* __restrict__ iids,
    __half* __restrict__ x,
    const float* __restrict__ wa1s, const float* __restrict__ wa1d,
    float* __restrict__ als1, float* __restrict__ ald1){
  int c  = threadIdx.x & 63;
  int rr = threadIdx.x >> 6;
  int r0 = blockIdx.x * 16 + rr * 4;
  float acc[4] = {0.f, 0.f, 0.f, 0.f};
  for (int k = 0; k < 256; k++) {
    float wv = cpw[k * 64 + c];
#pragma unroll
    for (int i = 0; i < 4; i++)
      acc[i] = fmaf(content[(size_t)(r0 + i) * 256 + k], wv, acc[i]);
  }
  float2 wsL = *(const float2*)(wa1s + 2 * c);
  float2 wdL = *(const float2*)(wa1d + 2 * c);
  float2 wsH = *(const float2*)(wa1s + 128 + 2 * c);
  float2 wdH = *(const float2*)(wa1d + 128 + 2 * c);
#pragma unroll
  for (int i = 0; i < 4; i++) {
    int r = r0 + i;
    if (r >= BB) continue;
    int iid = iids[r];
    size_t node = (size_t)(NUU + iid);
    float hi = acc[i] + cpb[c];
    float lo = iemb[(size_t)iid * 64 + c];
    x[node * 128 + 64 + c] = __float2half(hi);
    x[node * 128 + c]      = __float2half(lo);
    float s0 = wsum64(lo * wsL.x + hi * wsH.x);
    float s1 = wsum64(lo * wsL.y + hi * wsH.y);
    float d0 = wsum64(lo * wdL.x + hi * wdH.x);
    float d1 = wsum64(lo * wdL.y + hi * wdH.y);
    if (c == 0) {
      *(float2*)(als1 + node * 2) = make_float2(s0, s1);
      *(float2*)(ald1 + node * 2) = make_float2(d0, d1);
    }
  }
}

// ---------------- CSR build via bucket sort ----------------
__global__ __launch_bounds__(256) void k_bin(const int* __restrict__ ei,
    int* __restrict__ bucket_cnt, int2* __restrict__ bucket_data){
  __shared__ int hist[NBUK];
  __shared__ int base[NBUK];
  int tid = threadIdx.x;
  int t0 = blockIdx.x * CHUNK;
  for (int i = tid; i < NBUK; i += 256) hist[i] = 0;
  __syncthreads();
  for (int i = tid; i < CHUNK; i += 256) {
    int t = t0 + i;
    if (t >= ETOT) break;
    int dst = (t < EE) ? ei[EE + t] : (t - EE);
    atomicAdd(&hist[dst >> 7], 1);
  }
  __syncthreads();
  for (int b = tid; b < NBUK; b += 256) {
    int c = hist[b];
    base[b] = c ? atomicAdd(&bucket_cnt[b], c) : 0;
    hist[b] = 0;
  }
  __syncthreads();
  for (int i = tid; i < CHUNK; i += 256) {
    int t = t0 + i;
    if (t >= ETOT) break;
    int src, dst;
    if (t < EE) { src = ei[t]; dst = ei[EE + t]; }
    else        { src = dst = t - EE; }
    int b = dst >> 7;
    int r = base[b] + atomicAdd(&hist[b], 1);
    if (r < CAP) bucket_data[(size_t)b * CAP + r] = make_int2(src, dst);
  }
}

__global__ void k_bscan(const int* __restrict__ cnt, int* __restrict__ bbase,
                        int* __restrict__ offs_end){
  int lane = threadIdx.x;   // 64 threads
  int carry = 0;
  for (int c0 = 0; c0 < NBUK; c0 += 64) {
    int i = c0 + lane;
    int v = (i < NBUK) ? cnt[i] : 0;
    int x = v;
#pragma unroll
    for (int d = 1; d < 64; d <<= 1) { int t = __shfl_up(x, d, 64); if (lane >= d) x += t; }
    if (i < NBUK) bbase[i] = carry + x - v;
    carry += __shfl(x, 63, 64);
  }
  if (lane == 0) *offs_end = carry;   // offs[ND] = ETOT
}

__global__ __launch_bounds__(256) void k_bucket(const int2* __restrict__ bucket_data,
    const int* __restrict__ bucket_cnt, const int* __restrict__ bbase,
    int* __restrict__ offs, int* __restrict__ csr){
  __shared__ int degL[128];
  __shared__ int curL[128];
  int b = blockIdx.x;
  int tid = threadIdx.x;
  int cnt = bucket_cnt[b];
  int base = bbase[b];
  if (tid < 128) degL[tid] = 0;
  __syncthreads();
  const int2* bd = bucket_data + (size_t)b * CAP;
  for (int i = tid; i < cnt; i += 256)
    atomicAdd(&degL[bd[i].y & 127], 1);
  __syncthreads();
  if (tid < 64) {   // wave 0: exclusive scan of 128 degs
    int v0 = degL[tid], v1 = degL[64 + tid];
    int s0 = v0, s1 = v1;
#pragma unroll
    for (int d = 1; d < 64; d <<= 1) {
      int t0 = __shfl_up(s0, d, 64); if (tid >= d) s0 += t0;
      int t1 = __shfl_up(s1, d, 64); if (tid >= d) s1 += t1;
    }
    int tot0 = __shfl(s0, 63, 64);
    int e0 = s0 - v0;
    int e1 = s1 - v1 + tot0;
    curL[tid] = e0; curL[64 + tid] = e1;
    int g0 = b * 128 + tid, g1 = b * 128 + 64 + tid;
    if (g0 < ND) offs[g0] = base + e0;
    if (g1 < ND) offs[g1] = base + e1;
  }
  __syncthreads();
  for (int i = tid; i < cnt; i += 256) {
    int2 e = bd[i];
    int p = atomicAdd(&curL[e.y & 127], 1);
    csr[base + p] = e.x;
  }
}

// ---------------- MFMA fp16 GEMM: C[M,N](f16) = A[M,128](f16) @ Bt[N,128]^T ----------------
template<int NT>   // N = NT*16
__global__ __launch_bounds__(256) void k_mfma(const __half* __restrict__ A,
    const __half* __restrict__ Bt, __half* __restrict__ C, int M){
  constexpr int N = NT * 16;
  int wid  = (blockIdx.x * 256 + threadIdx.x) >> 6;
  int lane = threadIdx.x & 63;
  int q = lane >> 4, mr = lane & 15;
  int r0 = wid * 32;
  if (r0 >= M) return;
  int row0 = min(r0 + mr, M - 1);
  int row1 = min(r0 + 16 + mr, M - 1);
  f4 acc[2][NT];
#pragma unroll
  for (int i = 0; i < 2; i++)
#pragma unroll
    for (int j = 0; j < NT; j++) acc[i][j] = (f4)0.f;
#pragma unroll
  for (int ks = 0; ks < 4; ks++) {
    int ko = ks * 32 + q * 8;
    h8 a0 = *(const h8*)(A + (size_t)row0 * 128 + ko);
    h8 a1 = *(const h8*)(A + (size_t)row1 * 128 + ko);
#pragma unroll
    for (int nt = 0; nt < NT; nt++) {
      h8 b = *(const h8*)(Bt + (size_t)(nt * 16 + mr) * 128 + ko);
      acc[0][nt] = __builtin_amdgcn_mfma_f32_16x16x32_f16(a0, b, acc[0][nt], 0, 0, 0);
      acc[1][nt] = __builtin_amdgcn_mfma_f32_16x16x32_f16(a1, b, acc[1][nt], 0, 0, 0);
    }
  }
#pragma unroll
  for (int mt = 0; mt < 2; mt++)
#pragma unroll
    for (int r = 0; r < 4; r++) {
      int row = r0 + mt * 16 + q * 4 + r;
      if (row < M) {
#pragma unroll
        for (int nt = 0; nt < NT; nt++)
          C[(size_t)row * N + nt * 16 + mr] = __float2half(acc[mt][nt][r]);
      }
    }
}

// ---------------- GAT aggregation, H=2 (layer 1) ----------------
// one wave per dst. Per edge: merged scalar s_load of src, ds_read_b128 p
// broadcast, 1 coalesced 256B row load, 2 FMA. 16 gathers in flight.
// csr is zero-padded 16 past ETOT so the unrolled loop never clamps:
// entries past e1 are valid node ids (or 0) and their p is 0 -> FMA adds 0.
__global__ __launch_bounds__(256) void k_agg2(const __half2* __restrict__ xw,
    const float* __restrict__ als, const float* __restrict__ ald,
    const int* __restrict__ offs, const int* __restrict__ csr,
    const float* __restrict__ bias, __half* __restrict__ out,
    const float* __restrict__ wa2s, const float* __restrict__ wa2d,
    float* __restrict__ als2, float* __restrict__ ald2, int n){
  __shared__ __align__(16) float pshare[4][2][64];
  int gw = (blockIdx.x * 256 + threadIdx.x) >> 6;
  int lane = threadIdx.x & 63;
  int ws = (threadIdx.x >> 6) & 3;
  if (gw >= n) return;
  int e0 = __builtin_amdgcn_readfirstlane(offs[gw]);
  int e1 = __builtin_amdgcn_readfirstlane(offs[gw + 1]);
  float2 aldv = *(const float2*)(ald + (size_t)gw * 2);
  bool lo = lane < 32;
  const float* myp = &pshare[ws][0][0] + (lo ? 0 : 64);
  float den0 = 0.f, den1 = 0.f, accx = 0.f, accy = 0.f;
  for (int base = e0; base < e1; base += 64) {
    int e = base + lane;
    bool valid = (e < e1);
    int srcv = valid ? csr[e] : 0;
    float p0 = 0.f, p1 = 0.f;
    if (valid) {
      float2 a = *(const float2*)(als + (size_t)srcv * 2);
      float v0 = a.x + aldv.x, v1 = a.y + aldv.y;
      v0 = fmaxf(v0, 0.2f * v0);
      v1 = fmaxf(v1, 0.2f * v1);
      p0 = __expf(v0); p1 = __expf(v1);
    }
    den0 += p0; den1 += p1;                  // per-lane partials; reduced at end
    pshare[ws][0][lane] = p0;
    pshare[ws][1][lane] = p1;                // same-wave DS ordering: write before read
    int cnt = min(e1 - base, 64);
    const int* cp = csr + base;              // wave-uniform -> merged s_load
    for (int j0 = 0; j0 < cnt; j0 += 16) {
      __half2 hv[16]; float pj[16];
#pragma unroll
      for (int q = 0; q < 4; q++) {
        float4 pv = *(const float4*)(myp + j0 + 4 * q);   // ds_read_b128 broadcast
        pj[4*q] = pv.x; pj[4*q+1] = pv.y; pj[4*q+2] = pv.z; pj[4*q+3] = pv.w;
      }
#pragma unroll
      for (int u = 0; u < 16; u++) {
        int sj = __builtin_amdgcn_readfirstlane(cp[j0 + u]);  // contiguous scalar loads
        hv[u] = xw[(size_t)sj * 64 + lane];  // SGPR base + lane offset, 16 in flight
      }
#pragma unroll
      for (int u = 0; u < 16; u++) {
        float2 fv = __half22float2(hv[u]);
        accx = fmaf(pj[u], fv.x, accx);
        accy = fmaf(pj[u], fv.y, accy);
      }
    }
  }
  float dt0 = wsum64(den0), dt1 = wsum64(den1);
  float den = (lo ? dt0 : dt1) + 1e-16f;
  float inv = 1.f / den;
  float2 b = *(const float2*)(bias + 2 * lane);
  float vx = accx * inv + b.x;
  float vy = accy * inv + b.y;
  vx = (vx > 0.f) ? vx : expm1f(vx);         // elu
  vy = (vy > 0.f) ? vy : expm1f(vy);
  *(__half2*)(out + (size_t)gw * 128 + 2 * lane) = __floats2half2_rn(vx, vy);
  float2 wsv = *(const float2*)(wa2s + 2 * lane);
  float2 wdv = *(const float2*)(wa2d + 2 * lane);
  float s_s = wsum64(vx * wsv.x + vy * wsv.y);
  float s_d = wsum64(vx * wdv.x + vy * wdv.y);
  if (lane == 0) { als2[gw] = s_s; ald2[gw] = s_d; }
}

// ---------------- GAT aggregation, H=1 (layer 2): 2 edges/instr, 8 in flight ----------------
__global__ __launch_bounds__(256) void k_agg1(const __half2* __restrict__ xw,
    const float* __restrict__ als, const float* __restrict__ ald,
    const int* __restrict__ offs, const int* __restrict__ csr,
    const float* __restrict__ bias, __half* __restrict__ out, int n){
  __shared__ float pshare[4][64];
  int gw = (blockIdx.x * 256 + threadIdx.x) >> 6;
  int lane = threadIdx.x & 63;
  int ws = (threadIdx.x >> 6) & 3;
  if (gw >= n) return;
  int e0 = __builtin_amdgcn_readfirstlane(offs[gw]);
  int e1 = __builtin_amdgcn_readfirstlane(offs[gw + 1]);
  float aldd = ald[gw];
  int hid = lane >> 5;
  int c = lane & 31;
  const float* myp = &pshare[ws][0] + hid;   // lanes<32 read p[j], >=32 read p[j+1]
  float den = 0.f, accx = 0.f, accy = 0.f;
  for (int base = e0; base < e1; base += 64) {
    int e = base + lane;
    bool valid = (e < e1);
    int srcv = valid ? csr[e] : 0;
    float p = 0.f;
    if (valid) {
      float v = als[srcv] + aldd;
      v = fmaxf(v, 0.2f * v);
      p = __expf(v);
    }
    den += p;
    pshare[ws][lane] = p;
    int cnt = min(e1 - base, 64);
    const int* cp = csr + base;
    for (int j0 = 0; j0 < cnt; j0 += 16) {
      __half2 hv[8]; float pj[8];
#pragma unroll
      for (int u = 0; u < 8; u++) {
        int j = j0 + 2 * u;
        int sj0 = __builtin_amdgcn_readfirstlane(cp[j]);       // merged s_loads
        int sj1 = __builtin_amdgcn_readfirstlane(cp[j + 1]);
        int sel = hid ? sj1 : sj0;           // 1 cndmask from 2 SGPRs
        hv[u] = xw[(size_t)sel * 32 + c];
        pj[u] = myp[j];                      // ds_read broadcast (2 addrs/wave)
      }
#pragma unroll
      for (int u = 0; u < 8; u++) {
        float2 fv = __half22float2(hv[u]);
        accx = fmaf(pj[u], fv.x, accx);
        accy = fmaf(pj[u], fv.y, accy);
      }
    }
  }
  accx += __shfl_xor(accx, 32, 64);
  accy += __shfl_xor(accy, 32, 64);
  float dent = wsum64(den);
  if (lane < 32) {
    float inv = 1.f / (dent + 1e-16f);
    float2 b = *(const float2*)(bias + 2 * c);
    float vx = accx * inv + b.x;
    float vy = accy * inv + b.y;
    *(__half2*)(out + (size_t)gw * 64 + 2 * c) = __floats2half2_rn(vx, vy);
  }
}

// ---------------- prediction head: 16 rows/block, LDS weight reuse ----------------
__global__ __launch_bounds__(256) void k_head(const float* __restrict__ uemb,
    const int* __restrict__ uids, const int* __restrict__ iids,
    const __half* __restrict__ x2, const float* __restrict__ pw1,
    const float* __restrict__ pb1, const float* __restrict__ pw2,
    const float* __restrict__ pb2, float* __restrict__ out, int B){
  __shared__ __align__(16) float pw1_s[192 * 64];  // 48KB
  __shared__ float comb_s[16][192];
  for (int i = threadIdx.x; i < 192 * 64 / 4; i += 256)
    ((float4*)pw1_s)[i] = ((const float4*)pw1)[i];
  int w = threadIdx.x >> 6, lane = threadIdx.x & 63;
#pragma unroll
  for (int rr = 0; rr < 4; rr++) {
    int r = w * 4 + rr;
    int b = blockIdx.x * 16 + r;
    if (b < B) {
      int uid = uids[b], iid = iids[b];
      comb_s[r][lane]       = uemb[(size_t)uid * 64 + lane];
      comb_s[r][64 + lane]  = __half2float(x2[(size_t)(NUU + iid) * 64 + lane]);
      comb_s[r][128 + lane] = __half2float(x2[(size_t)uid * 64 + lane]);
    }
  }
  __syncthreads();
  float pw2v = pw2[lane];
  float pb1v = pb1[lane];
#pragma unroll
  for (int rr = 0; rr < 4; rr++) {
    int r = w * 4 + rr;
    int b = blockIdx.x * 16 + r;
    if (b >= B) continue;
    float acc = pb1v;
#pragma unroll 8
    for (int j = 0; j < 192; j++)
      acc = fmaf(comb_s[r][j], pw1_s[j * 64 + lane], acc);
    acc = fmaxf(acc, 0.f);
    float prod = wsum64(acc * pw2v);
    if (lane == 0) out[b] = prod + pb2[0];
  }
}

// ---------------- launcher ----------------
extern "C" void kernel_launch(void* const* d_in, const int* in_sizes, int n_in,
                              void* d_out, int out_size, void* d_ws, size_t ws_size,
                              hipStream_t stream) {
  (void)in_sizes; (void)n_in; (void)out_size; (void)ws_size;
  const int*   user_ids = (const int*)  d_in[0];
  const int*   item_ids = (const int*)  d_in[1];
  const float* content  = (const float*)d_in[2];
  const int*   edge_idx = (const int*)  d_in[3];
  const float* uemb     = (const float*)d_in[4];
  const float* iemb     = (const float*)d_in[5];
  const float* cp_w     = (const float*)d_in[6];
  const float* cp_b     = (const float*)d_in[7];
  const float* w1       = (const float*)d_in[8];
  const float* asrc1    = (const float*)d_in[9];
  const float* adst1    = (const float*)d_in[10];
  const float* b1       = (const float*)d_in[11];
  const float* w2       = (const float*)d_in[12];
  const float* asrc2    = (const float*)d_in[13];
  const float* adst2    = (const float*)d_in[14];
  const float* b2       = (const float*)d_in[15];
  const float* pw1      = (const float*)d_in[16];
  const float* pb1      = (const float*)d_in[17];
  const float* pw2      = (const float*)d_in[18];
  const float* pb2      = (const float*)d_in[19];
  float* out = (float*)d_out;

  // workspace layout (~128 MB)
  __half* x    = (__half*)d_ws;                        // [ND,128] f16; reused as x1
  __half* xw   = x + (size_t)ND * 128;                 // [ND,128] f16 xw1; L2: xw2 + out2
  float* als1  = (float*)(xw + (size_t)ND * 128);      // [ND,2]
  float* ald1  = als1 + (size_t)ND * 2;                // [ND,2]
  float* als2  = ald1 + (size_t)ND * 2;                // [ND]
  float* ald2  = als2 + ND;                            // [ND]
  int* offs    = (int*)(ald2 + ND);                    // [ND+4]
  int* bcnt    = offs + ND + 4;                        // [NBUK]
  int* bbase   = bcnt + NBUK;                          // [NBUK]
  int* csr     = bbase + NBUK;                         // [ETOT+16] (zero-padded tail)
  int2* bdata  = (int2*)(csr + ETOT + 16);             // [NBUK*CAP] 8B-aligned
  __half* Wt1  = (__half*)(bdata + (size_t)NBUK * CAP); // [128,128]
  __half* Wt2  = Wt1 + 16384;                          // [64,128]
  float* wa1s  = (float*)(Wt2 + 8192);                 // [128,2]
  float* wa1d  = wa1s + 256;                           // [128,2]
  float* wa2s  = wa1d + 256;                           // [128]
  float* wa2d  = wa2s + 128;                           // [128]
  __half* xw2  = xw;                                   // [ND,64]
  __half* out2 = xw + (size_t)ND * 64;                 // [ND,64]

  hipMemsetAsync(x, 0, (size_t)ND * 128 * sizeof(__half), stream);
  hipMemsetAsync(als1, 0, (size_t)ND * 4 * sizeof(float), stream);  // als1+ald1
  hipMemsetAsync(bcnt, 0, NBUK * sizeof(int), stream);
  hipMemsetAsync(csr + ETOT, 0, 16 * sizeof(int), stream);          // safe overread pad

  k_conv<<<96, 256, 0, stream>>>(w1, w2, Wt1, Wt2);
  k_wa<<<1, 128, 0, stream>>>(w1, asrc1, adst1, w2, asrc2, adst2, wa1s, wa1d, wa2s, wa2d);

  k_users<<<BB * 64 / 256, 256, 0, stream>>>(user_ids, uemb, x, wa1s, wa1d, als1, ald1);
  k_items<<<BB / 16, 256, 0, stream>>>(content, cp_w, cp_b, iemb, item_ids, x,
                                       wa1s, wa1d, als1, ald1);

  // CSR build: bucket sort
  k_bin<<<NCH, 256, 0, stream>>>(edge_idx, bcnt, bdata);
  k_bscan<<<1, 64, 0, stream>>>(bcnt, bbase, offs + ND);
  k_bucket<<<NBUK, 256, 0, stream>>>(bdata, bcnt, bbase, offs, csr);

  // ----- GAT layer 1 (H=2) -----
  k_mfma<8><<<(ND + 127) / 128, 256, 0, stream>>>(x, Wt1, xw, ND);
  k_agg2<<<(ND * 64 + 255) / 256, 256, 0, stream>>>((const __half2*)xw, als1, ald1,
                                                    offs, csr, b1, x,
                                                    wa2s, wa2d, als2, ald2, ND);

  // ----- GAT layer 2 (H=1) -----
  k_mfma<4><<<(ND + 127) / 128, 256, 0, stream>>>(x, Wt2, xw2, ND);
  k_agg1<<<(ND * 64 + 255) / 256, 256, 0, stream>>>((const __half2*)xw2, als2, ald2,
                                                    offs, csr, b2, out2, ND);

  // ----- head -----
  k_head<<<(BB + 15) / 16, 256, 0, stream>>>(uemb, user_ids, item_ids, out2,
                                             pw1, pb1, pw2, pb2, out, BB);
}

// Round 7
// 517.836 us; speedup vs baseline: 1.1052x; 1.0176x over previous
//
#include <hip/hip_runtime.h>
#include <hip/hip_fp16.h>
#include <math.h>

// Problem constants (match reference)
static constexpr int ND  = 150000;   // total nodes
static constexpr int NUU = 100000;   // num users
static constexpr int BB  = 16384;    // batch
static constexpr int EE  = 2000000;  // edges (before self loops)
static constexpr int ETOT = EE + ND; // edges incl self loops

// bucket sort params
static constexpr int NBUK  = (ND + 127) >> 7;          // 1172 buckets of 128 nodes
static constexpr int CAP   = 4096;                     // per-bucket capacity (avg ~1835)
static constexpr int CHUNK = 8192;
static constexpr int NCH   = (ETOT + CHUNK - 1) / CHUNK;

typedef _Float16 h8 __attribute__((ext_vector_type(8)));
typedef float    f4 __attribute__((ext_vector_type(4)));

// ---------------- wave helpers ----------------
__device__ __forceinline__ float wsum64(float v){
#pragma unroll
  for (int d = 32; d > 0; d >>= 1) v += __shfl_xor(v, d, 64);
  return v;
}

// ---------------- weight prep: fp16 transpose + wa = W @ a^T ----------------
__global__ __launch_bounds__(256) void k_prep(const float* __restrict__ w1,
    const float* __restrict__ w2, __half* __restrict__ Wt1, __half* __restrict__ Wt2,
    const float* __restrict__ asrc1, const float* __restrict__ adst1,
    const float* __restrict__ asrc2, const float* __restrict__ adst2,
    float* __restrict__ wa1s, float* __restrict__ wa1d,
    float* __restrict__ wa2s, float* __restrict__ wa2d){
  if (blockIdx.x < 96) {
    int t = blockIdx.x * 256 + threadIdx.x;
    if (t < 16384) {
      int n = t >> 7, k = t & 127;
      Wt1[t] = __float2half(w1[k * 128 + n]);
    } else if (t < 24576) {
      int u = t - 16384;
      int n = u >> 7, k = u & 127;
      Wt2[u] = __float2half(w2[k * 64 + n]);
    }
  } else if (threadIdx.x < 128) {
    int k = threadIdx.x;  // 0..127
    float s0 = 0.f, s1 = 0.f, d0 = 0.f, d1 = 0.f, s2 = 0.f, d2 = 0.f;
    for (int c = 0; c < 64; c++) {
      float wA = w1[k * 128 + c];
      float wB = w1[k * 128 + 64 + c];
      s0 = fmaf(wA, asrc1[c], s0);       d0 = fmaf(wA, adst1[c], d0);
      s1 = fmaf(wB, asrc1[64 + c], s1);  d1 = fmaf(wB, adst1[64 + c], d1);
      float wC = w2[k * 64 + c];
      s2 = fmaf(wC, asrc2[c], s2);       d2 = fmaf(wC, adst2[c], d2);
    }
    wa1s[k * 2] = s0; wa1s[k * 2 + 1] = s1;
    wa1d[k * 2] = d0; wa1d[k * 2 + 1] = d1;
    wa2s[k] = s2; wa2d[k] = d2;
  }
}

// ---------------- fused input scatter (fp16 x) + layer-1 scores ----------------
static constexpr int NB_USERS = BB * 64 / 256;   // 4096
static constexpr int NB_ITEMS = BB / 16;         // 1024

__global__ __launch_bounds__(256) void k_scatter(const int* __restrict__ uids,
    const float* __restrict__ uemb,
    const float* __restrict__ content, const float* __restrict__ cpw,
    const float* __restrict__ cpb, const float* __restrict__ iemb,
    const int* __restrict__ iids, __half* __restrict__ x,
    const float* __restrict__ wa1s, const float* __restrict__ wa1d,
    float* __restrict__ als1, float* __restrict__ ald1){
  if (blockIdx.x < NB_USERS) {
    int t = blockIdx.x * 256 + threadIdx.x;
    int b = t >> 6, c = t & 63;          // one wave per row
    int uid = uids[b];
    float u = uemb[(size_t)uid * 64 + c];
    x[(size_t)uid * 128 + c] = __float2half(u);
    float2 ws = *(const float2*)(wa1s + 2 * c);
    float2 wd = *(const float2*)(wa1d + 2 * c);
    float s0 = wsum64(u * ws.x);
    float s1 = wsum64(u * ws.y);
    float d0 = wsum64(u * wd.x);
    float d1 = wsum64(u * wd.y);
    if (c == 0) {
      *(float2*)(als1 + (size_t)uid * 2) = make_float2(s0, s1);
      *(float2*)(ald1 + (size_t)uid * 2) = make_float2(d0, d1);
    }
  } else {
    int bid = blockIdx.x - NB_USERS;
    int c  = threadIdx.x & 63;
    int rr = threadIdx.x >> 6;
    int r0 = bid * 16 + rr * 4;
    float acc[4] = {0.f, 0.f, 0.f, 0.f};
    for (int k = 0; k < 256; k++) {
      float wv = cpw[k * 64 + c];
#pragma unroll
      for (int i = 0; i < 4; i++)
        acc[i] = fmaf(content[(size_t)(r0 + i) * 256 + k], wv, acc[i]);
    }
    float2 wsL = *(const float2*)(wa1s + 2 * c);
    float2 wdL = *(const float2*)(wa1d + 2 * c);
    float2 wsH = *(const float2*)(wa1s + 128 + 2 * c);
    float2 wdH = *(const float2*)(wa1d + 128 + 2 * c);
#pragma unroll
    for (int i = 0; i < 4; i++) {
      int r = r0 + i;
      int iid = iids[r];
      size_t node = (size_t)(NUU + iid);
      float hi = acc[i] + cpb[c];
      float lo = iemb[(size_t)iid * 64 + c];
      x[node * 128 + 64 + c] = __float2half(hi);
      x[node * 128 + c]      = __float2half(lo);
      float s0 = wsum64(lo * wsL.x + hi * wsH.x);
      float s1 = wsum64(lo * wsL.y + hi * wsH.y);
      float d0 = wsum64(lo * wdL.x + hi * wdH.x);
      float d1 = wsum64(lo * wdL.y + hi * wdH.y);
      if (c == 0) {
        *(float2*)(als1 + node * 2) = make_float2(s0, s1);
        *(float2*)(ald1 + node * 2) = make_float2(d0, d1);
      }
    }
  }
}

// ---------------- CSR build via bucket sort ----------------
__global__ __launch_bounds__(256) void k_bin(const int* __restrict__ ei,
    int* __restrict__ bucket_cnt, int2* __restrict__ bucket_data){
  __shared__ int hist[NBUK];
  __shared__ int base[NBUK];
  int tid = threadIdx.x;
  int t0 = blockIdx.x * CHUNK;
  for (int i = tid; i < NBUK; i += 256) hist[i] = 0;
  __syncthreads();
  for (int i = tid; i < CHUNK; i += 256) {
    int t = t0 + i;
    if (t >= ETOT) break;
    int dst = (t < EE) ? ei[EE + t] : (t - EE);
    atomicAdd(&hist[dst >> 7], 1);
  }
  __syncthreads();
  for (int b = tid; b < NBUK; b += 256) {
    int c = hist[b];
    base[b] = c ? atomicAdd(&bucket_cnt[b], c) : 0;
    hist[b] = 0;
  }
  __syncthreads();
  for (int i = tid; i < CHUNK; i += 256) {
    int t = t0 + i;
    if (t >= ETOT) break;
    int src, dst;
    if (t < EE) { src = ei[t]; dst = ei[EE + t]; }
    else        { src = dst = t - EE; }
    int b = dst >> 7;
    int r = base[b] + atomicAdd(&hist[b], 1);
    if (r < CAP) bucket_data[(size_t)b * CAP + r] = make_int2(src, dst);
  }
}

__global__ void k_bscan(const int* __restrict__ cnt, int* __restrict__ bbase,
                        int* __restrict__ offs_end, int* __restrict__ csr_pad){
  int lane = threadIdx.x;   // 64 threads
  if (lane < 16) csr_pad[lane] = 0;          // zero the csr overread pad
  int carry = 0;
  for (int c0 = 0; c0 < NBUK; c0 += 64) {
    int i = c0 + lane;
    int v = (i < NBUK) ? cnt[i] : 0;
    int x = v;
#pragma unroll
    for (int d = 1; d < 64; d <<= 1) { int t = __shfl_up(x, d, 64); if (lane >= d) x += t; }
    if (i < NBUK) bbase[i] = carry + x - v;
    carry += __shfl(x, 63, 64);
  }
  if (lane == 0) *offs_end = carry;   // offs[ND] = ETOT
}

__global__ __launch_bounds__(256) void k_bucket(const int2* __restrict__ bucket_data,
    const int* __restrict__ bucket_cnt, const int* __restrict__ bbase,
    int* __restrict__ offs, int* __restrict__ csr){
  __shared__ int degL[128];
  __shared__ int curL[128];
  int b = blockIdx.x;
  int tid = threadIdx.x;
  int cnt = bucket_cnt[b];
  int base = bbase[b];
  if (tid < 128) degL[tid] = 0;
  __syncthreads();
  const int2* bd = bucket_data + (size_t)b * CAP;
  for (int i = tid; i < cnt; i += 256)
    atomicAdd(&degL[bd[i].y & 127], 1);
  __syncthreads();
  if (tid < 64) {   // wave 0: exclusive scan of 128 degs
    int v0 = degL[tid], v1 = degL[64 + tid];
    int s0 = v0, s1 = v1;
#pragma unroll
    for (int d = 1; d < 64; d <<= 1) {
      int t0 = __shfl_up(s0, d, 64); if (tid >= d) s0 += t0;
      int t1 = __shfl_up(s1, d, 64); if (tid >= d) s1 += t1;
    }
    int tot0 = __shfl(s0, 63, 64);
    int e0 = s0 - v0;
    int e1 = s1 - v1 + tot0;
    curL[tid] = e0; curL[64 + tid] = e1;
    int g0 = b * 128 + tid, g1 = b * 128 + 64 + tid;
    if (g0 < ND) offs[g0] = base + e0;
    if (g1 < ND) offs[g1] = base + e1;
  }
  __syncthreads();
  for (int i = tid; i < cnt; i += 256) {
    int2 e = bd[i];
    int p = atomicAdd(&curL[e.y & 127], 1);
    csr[base + p] = e.x;
  }
}

// ---------------- MFMA fp16 GEMM: C[M,N](f16) = A[M,128](f16) @ Bt[N,128]^T ----------------
template<int NT>   // N = NT*16
__global__ __launch_bounds__(256) void k_mfma(const __half* __restrict__ A,
    const __half* __restrict__ Bt, __half* __restrict__ C, int M){
  constexpr int N = NT * 16;
  int wid  = (blockIdx.x * 256 + threadIdx.x) >> 6;
  int lane = threadIdx.x & 63;
  int q = lane >> 4, mr = lane & 15;
  int r0 = wid * 32;
  if (r0 >= M) return;
  int row0 = min(r0 + mr, M - 1);
  int row1 = min(r0 + 16 + mr, M - 1);
  f4 acc[2][NT];
#pragma unroll
  for (int i = 0; i < 2; i++)
#pragma unroll
    for (int j = 0; j < NT; j++) acc[i][j] = (f4)0.f;
#pragma unroll
  for (int ks = 0; ks < 4; ks++) {
    int ko = ks * 32 + q * 8;
    h8 a0 = *(const h8*)(A + (size_t)row0 * 128 + ko);
    h8 a1 = *(const h8*)(A + (size_t)row1 * 128 + ko);
#pragma unroll
    for (int nt = 0; nt < NT; nt++) {
      h8 b = *(const h8*)(Bt + (size_t)(nt * 16 + mr) * 128 + ko);
      acc[0][nt] = __builtin_amdgcn_mfma_f32_16x16x32_f16(a0, b, acc[0][nt], 0, 0, 0);
      acc[1][nt] = __builtin_amdgcn_mfma_f32_16x16x32_f16(a1, b, acc[1][nt], 0, 0, 0);
    }
  }
#pragma unroll
  for (int mt = 0; mt < 2; mt++)
#pragma unroll
    for (int r = 0; r < 4; r++) {
      int row = r0 + mt * 16 + q * 4 + r;
      if (row < M) {
#pragma unroll
        for (int nt = 0; nt < NT; nt++)
          C[(size_t)row * N + nt * 16 + mr] = __float2half(acc[mt][nt][r]);
      }
    }
}

// ---------------- GAT aggregation, H=2 (layer 1) ----------------
__global__ __launch_bounds__(256) void k_agg2(const __half2* __restrict__ xw,
    const float* __restrict__ als, const float* __restrict__ ald,
    const int* __restrict__ offs, const int* __restrict__ csr,
    const float* __restrict__ bias, __half* __restrict__ out,
    const float* __restrict__ wa2s, const float* __restrict__ wa2d,
    float* __restrict__ als2, float* __restrict__ ald2, int n){
  __shared__ __align__(16) float pshare[4][2][64];
  int gw = (blockIdx.x * 256 + threadIdx.x) >> 6;
  int lane = threadIdx.x & 63;
  int ws = (threadIdx.x >> 6) & 3;
  if (gw >= n) return;
  int e0 = __builtin_amdgcn_readfirstlane(offs[gw]);
  int e1 = __builtin_amdgcn_readfirstlane(offs[gw + 1]);
  float2 aldv = *(const float2*)(ald + (size_t)gw * 2);
  bool lo = lane < 32;
  const float* myp = &pshare[ws][0][0] + (lo ? 0 : 64);
  float den0 = 0.f, den1 = 0.f, accx = 0.f, accy = 0.f;
  for (int base = e0; base < e1; base += 64) {
    int e = base + lane;
    bool valid = (e < e1);
    int srcv = valid ? csr[e] : 0;
    float p0 = 0.f, p1 = 0.f;
    if (valid) {
      float2 a = *(const float2*)(als + (size_t)srcv * 2);
      float v0 = a.x + aldv.x, v1 = a.y + aldv.y;
      v0 = fmaxf(v0, 0.2f * v0);
      v1 = fmaxf(v1, 0.2f * v1);
      p0 = __expf(v0); p1 = __expf(v1);
    }
    den0 += p0; den1 += p1;                  // per-lane partials; reduced at end
    pshare[ws][0][lane] = p0;
    pshare[ws][1][lane] = p1;                // same-wave DS ordering: write before read
    int cnt = min(e1 - base, 64);
    const int* cp = csr + base;              // wave-uniform -> merged s_load
    for (int j0 = 0; j0 < cnt; j0 += 16) {
      __half2 hv[16]; float pj[16];
#pragma unroll
      for (int q = 0; q < 4; q++) {
        float4 pv = *(const float4*)(myp + j0 + 4 * q);   // ds_read_b128 broadcast
        pj[4*q] = pv.x; pj[4*q+1] = pv.y; pj[4*q+2] = pv.z; pj[4*q+3] = pv.w;
      }
#pragma unroll
      for (int u = 0; u < 16; u++) {
        int sj = __builtin_amdgcn_readfirstlane(cp[j0 + u]);  // contiguous scalar loads
        hv[u] = xw[(size_t)sj * 64 + lane];  // SGPR base + lane offset, 16 in flight
      }
#pragma unroll
      for (int u = 0; u < 16; u++) {
        float2 fv = __half22float2(hv[u]);
        accx = fmaf(pj[u], fv.x, accx);
        accy = fmaf(pj[u], fv.y, accy);
      }
    }
  }
  float dt0 = wsum64(den0), dt1 = wsum64(den1);
  float den = (lo ? dt0 : dt1) + 1e-16f;
  float inv = 1.f / den;
  float2 b = *(const float2*)(bias + 2 * lane);
  float vx = accx * inv + b.x;
  float vy = accy * inv + b.y;
  vx = (vx > 0.f) ? vx : expm1f(vx);         // elu
  vy = (vy > 0.f) ? vy : expm1f(vy);
  *(__half2*)(out + (size_t)gw * 128 + 2 * lane) = __floats2half2_rn(vx, vy);
  float2 wsv = *(const float2*)(wa2s + 2 * lane);
  float2 wdv = *(const float2*)(wa2d + 2 * lane);
  float s_s = wsum64(vx * wsv.x + vy * wsv.y);
  float s_d = wsum64(vx * wdv.x + vy * wdv.y);
  if (lane == 0) { als2[gw] = s_s; ald2[gw] = s_d; }
}

// ---------------- GAT aggregation, H=1 (layer 2): 2 edges/instr, 8 in flight ----------------
__global__ __launch_bounds__(256) void k_agg1(const __half2* __restrict__ xw,
    const float* __restrict__ als, const float* __restrict__ ald,
    const int* __restrict__ offs, const int* __restrict__ csr,
    const float* __restrict__ bias, __half* __restrict__ out, int n){
  __shared__ float pshare[4][64];
  int gw = (blockIdx.x * 256 + threadIdx.x) >> 6;
  int lane = threadIdx.x & 63;
  int ws = (threadIdx.x >> 6) & 3;
  if (gw >= n) return;
  int e0 = __builtin_amdgcn_readfirstlane(offs[gw]);
  int e1 = __builtin_amdgcn_readfirstlane(offs[gw + 1]);
  float aldd = ald[gw];
  int hid = lane >> 5;
  int c = lane & 31;
  const float* myp = &pshare[ws][0] + hid;   // lanes<32 read p[j], >=32 read p[j+1]
  float den = 0.f, accx = 0.f, accy = 0.f;
  for (int base = e0; base < e1; base += 64) {
    int e = base + lane;
    bool valid = (e < e1);
    int srcv = valid ? csr[e] : 0;
    float p = 0.f;
    if (valid) {
      float v = als[srcv] + aldd;
      v = fmaxf(v, 0.2f * v);
      p = __expf(v);
    }
    den += p;
    pshare[ws][lane] = p;
    int cnt = min(e1 - base, 64);
    const int* cp = csr + base;
    for (int j0 = 0; j0 < cnt; j0 += 16) {
      __half2 hv[8]; float pj[8];
#pragma unroll
      for (int u = 0; u < 8; u++) {
        int j = j0 + 2 * u;
        int sj0 = __builtin_amdgcn_readfirstlane(cp[j]);       // merged s_loads
        int sj1 = __builtin_amdgcn_readfirstlane(cp[j + 1]);   // pad makes overread safe
        int sel = hid ? sj1 : sj0;           // 1 cndmask from 2 SGPRs
        hv[u] = xw[(size_t)sel * 32 + c];
        pj[u] = myp[j];                      // ds_read broadcast (2 addrs/wave)
      }
#pragma unroll
      for (int u = 0; u < 8; u++) {
        float2 fv = __half22float2(hv[u]);
        accx = fmaf(pj[u], fv.x, accx);
        accy = fmaf(pj[u], fv.y, accy);
      }
    }
  }
  accx += __shfl_xor(accx, 32, 64);
  accy += __shfl_xor(accy, 32, 64);
  float dent = wsum64(den);
  if (lane < 32) {
    float inv = 1.f / (dent + 1e-16f);
    float2 b = *(const float2*)(bias + 2 * c);
    float vx = accx * inv + b.x;
    float vy = accy * inv + b.y;
    *(__half2*)(out + (size_t)gw * 64 + 2 * c) = __floats2half2_rn(vx, vy);
  }
}

// ---------------- prediction head: register-tiled 64x64 GEMM, K=192 ----------------
// block = 64 rows x 64 cols, 256 threads, 4x4 per thread, float4 LDS reads.
__global__ __launch_bounds__(256) void k_head(const float* __restrict__ uemb,
    const int* __restrict__ uids, const int* __restrict__ iids,
    const __half* __restrict__ x2, const float* __restrict__ pw1,
    const float* __restrict__ pb1, const float* __restrict__ pw2,
    const float* __restrict__ pb2, float* __restrict__ out, int B){
  __shared__ __align__(16) float As[64][196];   // 49KB (196: float4-aligned rows, pad)
  __shared__ __align__(16) float Ws[192][64];   // 48KB
  int tid = threadIdx.x;
  for (int i = tid; i < 192 * 64 / 4; i += 256)
    ((float4*)&Ws[0][0])[i] = ((const float4*)pw1)[i];
  int w = tid >> 6, lane = tid & 63;
  int rbase = blockIdx.x * 64;
  for (int r = w; r < 64; r += 4) {
    int b = rbase + r;                          // B divisible by 64
    int uid = uids[b], iid = iids[b];
    As[r][lane]       = uemb[(size_t)uid * 64 + lane];
    As[r][64 + lane]  = __half2float(x2[(size_t)(NUU + iid) * 64 + lane]);
    As[r][128 + lane] = __half2float(x2[(size_t)uid * 64 + lane]);
  }
  __syncthreads();
  int tm = (tid >> 4) * 4;    // 0..60
  int tn = (tid & 15) * 4;    // 0..60
  float acc[4][4];
#pragma unroll
  for (int i = 0; i < 4; i++)
#pragma unroll
    for (int j = 0; j < 4; j++) acc[i][j] = 0.f;
  for (int k = 0; k < 192; k += 4) {
    float4 a[4], wv[4];
#pragma unroll
    for (int i = 0; i < 4; i++) a[i] = *(const float4*)&As[tm + i][k];
#pragma unroll
    for (int q = 0; q < 4; q++) wv[q] = *(const float4*)&Ws[k + q][tn];
#pragma unroll
    for (int i = 0; i < 4; i++) {
      acc[i][0] = fmaf(a[i].x, wv[0].x, acc[i][0]);
      acc[i][1] = fmaf(a[i].x, wv[0].y, acc[i][1]);
      acc[i][2] = fmaf(a[i].x, wv[0].z, acc[i][2]);
      acc[i][3] = fmaf(a[i].x, wv[0].w, acc[i][3]);
      acc[i][0] = fmaf(a[i].y, wv[1].x, acc[i][0]);
      acc[i][1] = fmaf(a[i].y, wv[1].y, acc[i][1]);
      acc[i][2] = fmaf(a[i].y, wv[1].z, acc[i][2]);
      acc[i][3] = fmaf(a[i].y, wv[1].w, acc[i][3]);
      acc[i][0] = fmaf(a[i].z, wv[2].x, acc[i][0]);
      acc[i][1] = fmaf(a[i].z, wv[2].y, acc[i][1]);
      acc[i][2] = fmaf(a[i].z, wv[2].z, acc[i][2]);
      acc[i][3] = fmaf(a[i].z, wv[2].w, acc[i][3]);
      acc[i][0] = fmaf(a[i].w, wv[3].x, acc[i][0]);
      acc[i][1] = fmaf(a[i].w, wv[3].y, acc[i][1]);
      acc[i][2] = fmaf(a[i].w, wv[3].z, acc[i][2]);
      acc[i][3] = fmaf(a[i].w, wv[3].w, acc[i][3]);
    }
  }
  // epilogue: relu + dot with pw2, reduce across the 16 tn-threads
  float4 pb1v = *(const float4*)(pb1 + tn);
  float4 pw2v = *(const float4*)(pw2 + tn);
  float pb2v = pb2[0];
#pragma unroll
  for (int i = 0; i < 4; i++) {
    float h0 = fmaxf(acc[i][0] + pb1v.x, 0.f);
    float h1 = fmaxf(acc[i][1] + pb1v.y, 0.f);
    float h2 = fmaxf(acc[i][2] + pb1v.z, 0.f);
    float h3 = fmaxf(acc[i][3] + pb1v.w, 0.f);
    float part = h0 * pw2v.x + h1 * pw2v.y + h2 * pw2v.z + h3 * pw2v.w;
#pragma unroll
    for (int d = 1; d < 16; d <<= 1) part += __shfl_xor(part, d, 64);
    if ((tid & 15) == 0) out[rbase + tm + i] = part + pb2v;
  }
}

// ---------------- launcher ----------------
extern "C" void kernel_launch(void* const* d_in, const int* in_sizes, int n_in,
                              void* d_out, int out_size, void* d_ws, size_t ws_size,
                              hipStream_t stream) {
  (void)in_sizes; (void)n_in; (void)out_size; (void)ws_size;
  const int*   user_ids = (const int*)  d_in[0];
  const int*   item_ids = (const int*)  d_in[1];
  const float* content  = (const float*)d_in[2];
  const int*   edge_idx = (const int*)  d_in[3];
  const float* uemb     = (const float*)d_in[4];
  const float* iemb     = (const float*)d_in[5];
  const float* cp_w     = (const float*)d_in[6];
  const float* cp_b     = (const float*)d_in[7];
  const float* w1       = (const float*)d_in[8];
  const float* asrc1    = (const float*)d_in[9];
  const float* adst1    = (const float*)d_in[10];
  const float* b1       = (const float*)d_in[11];
  const float* w2       = (const float*)d_in[12];
  const float* asrc2    = (const float*)d_in[13];
  const float* adst2    = (const float*)d_in[14];
  const float* b2       = (const float*)d_in[15];
  const float* pw1      = (const float*)d_in[16];
  const float* pb1      = (const float*)d_in[17];
  const float* pw2      = (const float*)d_in[18];
  const float* pb2      = (const float*)d_in[19];
  float* out = (float*)d_out;

  // workspace layout (~128 MB); als1/ald1/bcnt contiguous -> one memset
  __half* x    = (__half*)d_ws;                        // [ND,128] f16; reused as x1
  __half* xw   = x + (size_t)ND * 128;                 // [ND,128] f16 xw1; L2: xw2 + out2
  float* als1  = (float*)(xw + (size_t)ND * 128);      // [ND,2]
  float* ald1  = als1 + (size_t)ND * 2;                // [ND,2]
  int* bcnt    = (int*)(ald1 + (size_t)ND * 2);        // [NBUK]  (memset with als1/ald1)
  float* als2  = (float*)(bcnt + NBUK);                // [ND]
  float* ald2  = als2 + ND;                            // [ND]
  int* offs    = (int*)(ald2 + ND);                    // [ND+4]
  int* bbase   = offs + ND + 4;                        // [NBUK]
  int* csr     = bbase + NBUK;                         // [ETOT+16] (pad zeroed by k_bscan)
  int2* bdata  = (int2*)(csr + ETOT + 16);             // [NBUK*CAP] 8B-aligned
  __half* Wt1  = (__half*)(bdata + (size_t)NBUK * CAP); // [128,128]
  __half* Wt2  = Wt1 + 16384;                          // [64,128]
  float* wa1s  = (float*)(Wt2 + 8192);                 // [128,2]
  float* wa1d  = wa1s + 256;                           // [128,2]
  float* wa2s  = wa1d + 256;                           // [128]
  float* wa2d  = wa2s + 128;                           // [128]
  __half* xw2  = xw;                                   // [ND,64]
  __half* out2 = xw + (size_t)ND * 64;                 // [ND,64]

  hipMemsetAsync(x, 0, (size_t)ND * 128 * sizeof(__half), stream);
  hipMemsetAsync(als1, 0, ((size_t)ND * 4 + NBUK) * sizeof(float), stream);

  k_prep<<<97, 256, 0, stream>>>(w1, w2, Wt1, Wt2, asrc1, adst1, asrc2, adst2,
                                 wa1s, wa1d, wa2s, wa2d);

  k_scatter<<<NB_USERS + NB_ITEMS, 256, 0, stream>>>(user_ids, uemb, content, cp_w,
                                                     cp_b, iemb, item_ids, x,
                                                     wa1s, wa1d, als1, ald1);

  // CSR build: bucket sort
  k_bin<<<NCH, 256, 0, stream>>>(edge_idx, bcnt, bdata);
  k_bscan<<<1, 64, 0, stream>>>(bcnt, bbase, offs + ND, csr + ETOT);
  k_bucket<<<NBUK, 256, 0, stream>>>(bdata, bcnt, bbase, offs, csr);

  // ----- GAT layer 1 (H=2) -----
  k_mfma<8><<<(ND + 127) / 128, 256, 0, stream>>>(x, Wt1, xw, ND);
  k_agg2<<<(ND * 64 + 255) / 256, 256, 0, stream>>>((const __half2*)xw, als1, ald1,
                                                    offs, csr, b1, x,
                                                    wa2s, wa2d, als2, ald2, ND);

  // ----- GAT layer 2 (H=1) -----
  k_mfma<4><<<(ND + 127) / 128, 256, 0, stream>>>(x, Wt2, xw2, ND);
  k_agg1<<<(ND * 64 + 255) / 256, 256, 0, stream>>>((const __half2*)xw2, als2, ald2,
                                                    offs, csr, b2, out2, ND);

  // ----- head -----
  k_head<<<BB / 64, 256, 0, stream>>>(uemb, user_ids, item_ids, out2,
                                      pw1, pb1, pw2, pb2, out, BB);
}

// Round 8
// 463.322 us; speedup vs baseline: 1.2353x; 1.1177x over previous
//
#include <hip/hip_runtime.h>
#include <hip/hip_fp16.h>
#include <math.h>

// Problem constants (match reference)
static constexpr int ND  = 150000;   // total nodes
static constexpr int NUU = 100000;   // num users
static constexpr int BB  = 16384;    // batch
static constexpr int EE  = 2000000;  // edges (before self loops)
static constexpr int ETOT = EE + ND; // edges incl self loops
static constexpr int MACT = 2 * BB;  // active nodes (touched by batch)

// bucket sort params
static constexpr int NBUK  = (ND + 127) >> 7;          // 1172 buckets of 128 nodes
static constexpr int CAP   = 4096;                     // per-bucket capacity (avg ~1835)
static constexpr int CHUNK = 8192;
static constexpr int NCH   = (ETOT + CHUNK - 1) / CHUNK;
static constexpr int NBMW  = (ND + 31) / 32;           // bitmap words (4688)

typedef _Float16 h8 __attribute__((ext_vector_type(8)));
typedef float    f4 __attribute__((ext_vector_type(4)));

// ---------------- wave helpers ----------------
__device__ __forceinline__ float wsum64(float v){
#pragma unroll
  for (int d = 32; d > 0; d >>= 1) v += __shfl_xor(v, d, 64);
  return v;
}

// ---------------- weight prep: fp16 transpose + wa = W @ a^T ----------------
__global__ __launch_bounds__(256) void k_prep(const float* __restrict__ w1,
    const float* __restrict__ w2, __half* __restrict__ Wt1, __half* __restrict__ Wt2,
    const float* __restrict__ asrc1, const float* __restrict__ adst1,
    const float* __restrict__ asrc2, const float* __restrict__ adst2,
    float* __restrict__ wa1s, float* __restrict__ wa1d,
    float* __restrict__ wa2s, float* __restrict__ wa2d){
  if (blockIdx.x < 96) {
    int t = blockIdx.x * 256 + threadIdx.x;
    if (t < 16384) {
      int n = t >> 7, k = t & 127;
      Wt1[t] = __float2half(w1[k * 128 + n]);
    } else if (t < 24576) {
      int u = t - 16384;
      int n = u >> 7, k = u & 127;
      Wt2[u] = __float2half(w2[k * 64 + n]);
    }
  } else if (threadIdx.x < 128) {
    int k = threadIdx.x;  // 0..127
    float s0 = 0.f, s1 = 0.f, d0 = 0.f, d1 = 0.f, s2 = 0.f, d2 = 0.f;
    for (int c = 0; c < 64; c++) {
      float wA = w1[k * 128 + c];
      float wB = w1[k * 128 + 64 + c];
      s0 = fmaf(wA, asrc1[c], s0);       d0 = fmaf(wA, adst1[c], d0);
      s1 = fmaf(wB, asrc1[64 + c], s1);  d1 = fmaf(wB, adst1[64 + c], d1);
      float wC = w2[k * 64 + c];
      s2 = fmaf(wC, asrc2[c], s2);       d2 = fmaf(wC, adst2[c], d2);
    }
    wa1s[k * 2] = s0; wa1s[k * 2 + 1] = s1;
    wa1d[k * 2] = d0; wa1d[k * 2 + 1] = d1;
    wa2s[k] = s2; wa2d[k] = d2;
  }
}

// ---------------- input scatter (compact fp16 xc) + flags/bitmap + L1 scores ----------------
static constexpr int NB_USERS = BB * 64 / 256;   // 4096
static constexpr int NB_ITEMS = BB / 16;         // 1024

__global__ __launch_bounds__(256) void k_scatter(const int* __restrict__ uids,
    const float* __restrict__ uemb,
    const float* __restrict__ content, const float* __restrict__ cpw,
    const float* __restrict__ cpb, const float* __restrict__ iemb,
    const int* __restrict__ iids, __half* __restrict__ xc,
    const float* __restrict__ wa1s, const float* __restrict__ wa1d,
    float* __restrict__ als1c, float* __restrict__ ald1,
    int* __restrict__ flags, unsigned* __restrict__ bitmap,
    int* __restrict__ nodeOfC){
  if (blockIdx.x < NB_USERS) {
    int t = blockIdx.x * 256 + threadIdx.x;
    int b = t >> 6, c = t & 63;          // one wave per user row; compact idx = b
    int uid = uids[b];
    float u = uemb[(size_t)uid * 64 + c];
    xc[(size_t)b * 128 + c]      = __float2half(u);
    xc[(size_t)b * 128 + 64 + c] = __float2half(0.f);
    float2 ws = *(const float2*)(wa1s + 2 * c);
    float2 wd = *(const float2*)(wa1d + 2 * c);
    float s0 = wsum64(u * ws.x);
    float s1 = wsum64(u * ws.y);
    float d0 = wsum64(u * wd.x);
    float d1 = wsum64(u * wd.y);
    if (c == 0) {
      *(float2*)(als1c + (size_t)b * 2) = make_float2(s0, s1);
      *(float2*)(ald1 + (size_t)uid * 2) = make_float2(d0, d1);
      flags[uid] = b;
      nodeOfC[b] = uid;
      atomicOr(&bitmap[uid >> 5], 1u << (uid & 31));
    }
  } else {
    int bid = blockIdx.x - NB_USERS;
    int c  = threadIdx.x & 63;
    int rr = threadIdx.x >> 6;
    int r0 = bid * 16 + rr * 4;
    float acc[4] = {0.f, 0.f, 0.f, 0.f};
    for (int k = 0; k < 256; k++) {
      float wv = cpw[k * 64 + c];
#pragma unroll
      for (int i = 0; i < 4; i++)
        acc[i] = fmaf(content[(size_t)(r0 + i) * 256 + k], wv, acc[i]);
    }
    float2 wsL = *(const float2*)(wa1s + 2 * c);
    float2 wdL = *(const float2*)(wa1d + 2 * c);
    float2 wsH = *(const float2*)(wa1s + 128 + 2 * c);
    float2 wdH = *(const float2*)(wa1d + 128 + 2 * c);
#pragma unroll
    for (int i = 0; i < 4; i++) {
      int r = r0 + i;
      int iid = iids[r];
      int node = NUU + iid;
      int cidx = BB + r;                 // compact idx for item r
      float hi = acc[i] + cpb[c];
      float lo = iemb[(size_t)iid * 64 + c];
      xc[(size_t)cidx * 128 + 64 + c] = __float2half(hi);
      xc[(size_t)cidx * 128 + c]      = __float2half(lo);
      float s0 = wsum64(lo * wsL.x + hi * wsH.x);
      float s1 = wsum64(lo * wsL.y + hi * wsH.y);
      float d0 = wsum64(lo * wdL.x + hi * wdH.x);
      float d1 = wsum64(lo * wdL.y + hi * wdH.y);
      if (c == 0) {
        *(float2*)(als1c + (size_t)cidx * 2) = make_float2(s0, s1);
        *(float2*)(ald1 + (size_t)node * 2) = make_float2(d0, d1);
        flags[node] = cidx;
        nodeOfC[cidx] = node;
        atomicOr(&bitmap[node >> 5], 1u << (node & 31));
      }
    }
  }
}

// ---------------- CSR build pass 1: bin edges, packed entry with activity bits ----------------
// entry = src | srcAct<<18 | dstAct<<19 | (dst&127)<<20
__global__ __launch_bounds__(256) void k_bin(const int* __restrict__ ei,
    const unsigned* __restrict__ bitmap, int* __restrict__ bcnt,
    int* __restrict__ bcntA, int* __restrict__ bcntB, int* __restrict__ bdata){
  __shared__ unsigned bm[NBMW];
  __shared__ int hist[NBUK], base[NBUK], histA[NBUK], histB[NBUK];
  int tid = threadIdx.x;
  int t0 = blockIdx.x * CHUNK;
  for (int i = tid; i < NBMW; i += 256) bm[i] = bitmap[i];
  for (int i = tid; i < NBUK; i += 256) { hist[i] = 0; histA[i] = 0; histB[i] = 0; }
  __syncthreads();
  for (int i = tid; i < CHUNK; i += 256) {
    int t = t0 + i;
    if (t >= ETOT) break;
    int src, dst;
    if (t < EE) { src = ei[t]; dst = ei[EE + t]; }
    else        { src = dst = t - EE; }
    int b = dst >> 7;
    atomicAdd(&hist[b], 1);
    if ((bm[src >> 5] >> (src & 31)) & 1) atomicAdd(&histA[b], 1);
    if ((bm[dst >> 5] >> (dst & 31)) & 1) atomicAdd(&histB[b], 1);
  }
  __syncthreads();
  for (int b = tid; b < NBUK; b += 256) {
    int c = hist[b];
    base[b] = c ? atomicAdd(&bcnt[b], c) : 0;
    hist[b] = 0;
    if (histA[b]) atomicAdd(&bcntA[b], histA[b]);
    if (histB[b]) atomicAdd(&bcntB[b], histB[b]);
  }
  __syncthreads();
  for (int i = tid; i < CHUNK; i += 256) {
    int t = t0 + i;
    if (t >= ETOT) break;
    int src, dst;
    if (t < EE) { src = ei[t]; dst = ei[EE + t]; }
    else        { src = dst = t - EE; }
    int b = dst >> 7;
    int sa = (bm[src >> 5] >> (src & 31)) & 1;
    int da = (bm[dst >> 5] >> (dst & 31)) & 1;
    int r = base[b] + atomicAdd(&hist[b], 1);
    if (r < CAP)
      bdata[(size_t)b * CAP + r] = src | (sa << 18) | (da << 19) | ((dst & 127) << 20);
  }
}

// ---------------- pass 2: three bucket scans ----------------
__device__ __forceinline__ int scan_bk(const int* __restrict__ cnt, int* __restrict__ bbase,
                                       int lane){
  int carry = 0;
  for (int c0 = 0; c0 < NBUK; c0 += 64) {
    int i = c0 + lane;
    int v = (i < NBUK) ? cnt[i] : 0;
    int x = v;
#pragma unroll
    for (int d = 1; d < 64; d <<= 1) { int t = __shfl_up(x, d, 64); if (lane >= d) x += t; }
    if (i < NBUK) bbase[i] = carry + x - v;
    carry += __shfl(x, 63, 64);
  }
  return carry;
}

__global__ void k_bscan(const int* __restrict__ bcnt, int* __restrict__ bbase,
    const int* __restrict__ bcntA, int* __restrict__ bbaseA,
    const int* __restrict__ bcntB, int* __restrict__ bbaseB,
    int* __restrict__ offsA_end, int* __restrict__ csrA, int* __restrict__ csrB){
  int lane = threadIdx.x;   // 64 threads
  scan_bk(bcnt, bbase, lane);
  int tA = scan_bk(bcntA, bbaseA, lane);
  int tB = scan_bk(bcntB, bbaseB, lane);
  if (lane == 0) *offsA_end = tA;
  if (lane < 16) { csrA[tA + lane] = 0; csrB[tB + lane] = 0; }
}

// ---------------- pass 3: per-bucket scan + filtered scatter into csrA/csrB ----------------
__global__ __launch_bounds__(256) void k_bucket(const int* __restrict__ bdata,
    const int* __restrict__ bcnt, const int* __restrict__ bbase,
    const int* __restrict__ bbaseA, const int* __restrict__ bbaseB,
    const int* __restrict__ flags,
    int* __restrict__ offsA, int* __restrict__ inactA,
    int* __restrict__ startB, int* __restrict__ degBv,
    int* __restrict__ csrA, int* __restrict__ csrB){
  __shared__ int degAll[128], degAct[128], curA[128], curB[128];
  int b = blockIdx.x;
  int tid = threadIdx.x;
  int cnt = bcnt[b];
  const int* bd = bdata + (size_t)b * CAP;
  if (tid < 128) { degAll[tid] = 0; degAct[tid] = 0; }
  __syncthreads();
  for (int i = tid; i < cnt; i += 256) {
    int e = bd[i];
    int d7 = (e >> 20) & 127;
    atomicAdd(&degAll[d7], 1);
    if ((e >> 18) & 1) atomicAdd(&degAct[d7], 1);
  }
  __syncthreads();
  if (tid < 64) {
    int g0 = b * 128 + tid, g1 = g0 + 64;
    int A0 = degAll[tid], A1 = degAll[64 + tid];
    int a0 = degAct[tid], a1 = degAct[64 + tid];
    // exclusive scan of active counts over 128 locals
    int s0 = a0, s1 = a1;
#pragma unroll
    for (int d = 1; d < 64; d <<= 1) {
      int t0 = __shfl_up(s0, d, 64); if (tid >= d) s0 += t0;
      int t1 = __shfl_up(s1, d, 64); if (tid >= d) s1 += t1;
    }
    int totA0 = __shfl(s0, 63, 64);
    int eA0 = s0 - a0, eA1 = s1 - a1 + totA0;
    int baseA = bbaseA[b];
    curA[tid] = baseA + eA0; curA[64 + tid] = baseA + eA1;
    if (g0 < ND) { offsA[g0] = baseA + eA0; inactA[g0] = A0 - a0; }
    if (g1 < ND) { offsA[g1] = baseA + eA1; inactA[g1] = A1 - a1; }
    // csrB: only active dsts, full degree
    int f0 = (g0 < ND) ? flags[g0] : -1;
    int f1 = (g1 < ND) ? flags[g1] : -1;
    int w0 = (f0 >= 0) ? A0 : 0, w1 = (f1 >= 0) ? A1 : 0;
    int t0 = w0, t1 = w1;
#pragma unroll
    for (int d = 1; d < 64; d <<= 1) {
      int u0 = __shfl_up(t0, d, 64); if (tid >= d) t0 += u0;
      int u1 = __shfl_up(t1, d, 64); if (tid >= d) t1 += u1;
    }
    int totB0 = __shfl(t0, 63, 64);
    int eB0 = t0 - w0, eB1 = t1 - w1 + totB0;
    int baseB = bbaseB[b];
    curB[tid] = baseB + eB0; curB[64 + tid] = baseB + eB1;
    if (f0 >= 0) { startB[f0] = baseB + eB0; degBv[f0] = A0; }
    if (f1 >= 0) { startB[f1] = baseB + eB1; degBv[f1] = A1; }
  }
  __syncthreads();
  for (int i = tid; i < cnt; i += 256) {
    int e = bd[i];
    int d7 = (e >> 20) & 127;
    int src = e & 0x3FFFF;
    if ((e >> 19) & 1) { int p = atomicAdd(&curB[d7], 1); csrB[p] = src; }
    if ((e >> 18) & 1) {
      int ci = flags[src];
      int p = atomicAdd(&curA[d7], 1);
      csrA[p] = ci;                      // store compact idx directly
    }
  }
}

// ---------------- MFMA fp16 GEMM: C[M,N](f16) = A[M,128](f16) @ Bt[N,128]^T ----------------
template<int NT>   // N = NT*16
__global__ __launch_bounds__(256) void k_mfma(const __half* __restrict__ A,
    const __half* __restrict__ Bt, __half* __restrict__ C, int M){
  constexpr int N = NT * 16;
  int wid  = (blockIdx.x * 256 + threadIdx.x) >> 6;
  int lane = threadIdx.x & 63;
  int q = lane >> 4, mr = lane & 15;
  int r0 = wid * 32;
  if (r0 >= M) return;
  int row0 = min(r0 + mr, M - 1);
  int row1 = min(r0 + 16 + mr, M - 1);
  f4 acc[2][NT];
#pragma unroll
  for (int i = 0; i < 2; i++)
#pragma unroll
    for (int j = 0; j < NT; j++) acc[i][j] = (f4)0.f;
#pragma unroll
  for (int ks = 0; ks < 4; ks++) {
    int ko = ks * 32 + q * 8;
    h8 a0 = *(const h8*)(A + (size_t)row0 * 128 + ko);
    h8 a1 = *(const h8*)(A + (size_t)row1 * 128 + ko);
#pragma unroll
    for (int nt = 0; nt < NT; nt++) {
      h8 b = *(const h8*)(Bt + (size_t)(nt * 16 + mr) * 128 + ko);
      acc[0][nt] = __builtin_amdgcn_mfma_f32_16x16x32_f16(a0, b, acc[0][nt], 0, 0, 0);
      acc[1][nt] = __builtin_amdgcn_mfma_f32_16x16x32_f16(a1, b, acc[1][nt], 0, 0, 0);
    }
  }
#pragma unroll
  for (int mt = 0; mt < 2; mt++)
#pragma unroll
    for (int r = 0; r < 4; r++) {
      int row = r0 + mt * 16 + q * 4 + r;
      if (row < M) {
#pragma unroll
        for (int nt = 0; nt < NT; nt++)
          C[(size_t)row * N + nt * 16 + mr] = __float2half(acc[mt][nt][r]);
      }
    }
}

// ---------------- gather blocks ----------------
template<int U>
__device__ __forceinline__ void gat2_blk(const int* __restrict__ cp, int j0,
    const float* __restrict__ myp, const __half2* __restrict__ xw, int lane,
    float& accx, float& accy){
  __half2 hv[U]; float pj[U];
#pragma unroll
  for (int u = 0; u < U; u++) {
    int sj = __builtin_amdgcn_readfirstlane(cp[j0 + u]);
    hv[u] = xw[(size_t)sj * 64 + lane];
    pj[u] = myp[j0 + u];
  }
#pragma unroll
  for (int u = 0; u < U; u++) {
    float2 fv = __half22float2(hv[u]);
    accx = fmaf(pj[u], fv.x, accx);
    accy = fmaf(pj[u], fv.y, accy);
  }
}

template<int U>   // U pairs = 2U edges
__device__ __forceinline__ void gat1_blk(const int* __restrict__ cp, int j0,
    const float* __restrict__ myp, const __half2* __restrict__ xw, int cw, int hid,
    float& accx, float& accy){
  __half2 hv[U]; float pj[U];
#pragma unroll
  for (int u = 0; u < U; u++) {
    int j = j0 + 2 * u;
    int s0 = __builtin_amdgcn_readfirstlane(cp[j]);
    int s1 = __builtin_amdgcn_readfirstlane(cp[j + 1]);
    int sel = hid ? s1 : s0;
    hv[u] = xw[(size_t)sel * 32 + cw];
    pj[u] = myp[j];
  }
#pragma unroll
  for (int u = 0; u < U; u++) {
    float2 fv = __half22float2(hv[u]);
    accx = fmaf(pj[u], fv.x, accx);
    accy = fmaf(pj[u], fv.y, accy);
  }
}

// ---------------- GAT layer 1 aggregation (H=2), filtered csrA ----------------
// inactive srcs contribute inact * exp(leaky(ald)) to den and 0 to acc.
__global__ __launch_bounds__(256) void k_agg2(const __half2* __restrict__ xwc,
    const float* __restrict__ als1c, const float* __restrict__ ald1,
    const int* __restrict__ offsA, const int* __restrict__ inactA,
    const int* __restrict__ csrA,
    const float* __restrict__ bias, __half* __restrict__ out,
    const float* __restrict__ wa2s, const float* __restrict__ wa2d,
    float* __restrict__ als2, float* __restrict__ ald2, int n){
  __shared__ float pshare[4][2][64];
  int gw = (blockIdx.x * 256 + threadIdx.x) >> 6;
  int lane = threadIdx.x & 63;
  int ws = (threadIdx.x >> 6) & 3;
  if (gw >= n) return;
  int e0 = __builtin_amdgcn_readfirstlane(offsA[gw]);
  int e1 = __builtin_amdgcn_readfirstlane(offsA[gw + 1]);
  int inact = __builtin_amdgcn_readfirstlane(inactA[gw]);
  float2 aldv = *(const float2*)(ald1 + (size_t)gw * 2);
  bool lo = lane < 32;
  const float* myp = &pshare[ws][0][0] + (lo ? 0 : 64);
  float den0 = 0.f, den1 = 0.f, accx = 0.f, accy = 0.f;
  for (int base = e0; base < e1; base += 64) {
    int e = base + lane;
    bool valid = (e < e1);
    int srcv = valid ? csrA[e] : 0;
    float p0 = 0.f, p1 = 0.f;
    if (valid) {
      float2 a = *(const float2*)(als1c + (size_t)srcv * 2);
      float v0 = a.x + aldv.x, v1 = a.y + aldv.y;
      v0 = fmaxf(v0, 0.2f * v0);
      v1 = fmaxf(v1, 0.2f * v1);
      p0 = __expf(v0); p1 = __expf(v1);
    }
    den0 += p0; den1 += p1;
    pshare[ws][0][lane] = p0;
    pshare[ws][1][lane] = p1;
    int cnt = min(e1 - base, 64);
    const int* cp = csrA + base;
    int j = 0;
    for (; j + 16 <= cnt; j += 16) gat2_blk<16>(cp, j, myp, xwc, lane, accx, accy);
    if (j + 8 <= cnt) { gat2_blk<8>(cp, j, myp, xwc, lane, accx, accy); j += 8; }
    if (j + 4 <= cnt) { gat2_blk<4>(cp, j, myp, xwc, lane, accx, accy); j += 4; }
    if (j + 2 <= cnt) { gat2_blk<2>(cp, j, myp, xwc, lane, accx, accy); j += 2; }
    if (j < cnt)        gat2_blk<1>(cp, j, myp, xwc, lane, accx, accy);
  }
  // inactive contribution to denominators (wave-uniform)
  float pin0 = __expf(fmaxf(aldv.x, 0.2f * aldv.x));
  float pin1 = __expf(fmaxf(aldv.y, 0.2f * aldv.y));
  float dt0 = wsum64(den0) + (float)inact * pin0;
  float dt1 = wsum64(den1) + (float)inact * pin1;
  float den = (lo ? dt0 : dt1) + 1e-16f;
  float inv = 1.f / den;
  float2 b = *(const float2*)(bias + 2 * lane);
  float vx = accx * inv + b.x;
  float vy = accy * inv + b.y;
  vx = (vx > 0.f) ? vx : expm1f(vx);         // elu
  vy = (vy > 0.f) ? vy : expm1f(vy);
  *(__half2*)(out + (size_t)gw * 128 + 2 * lane) = __floats2half2_rn(vx, vy);
  float2 wsv = *(const float2*)(wa2s + 2 * lane);
  float2 wdv = *(const float2*)(wa2d + 2 * lane);
  float s_s = wsum64(vx * wsv.x + vy * wsv.y);
  float s_d = wsum64(vx * wdv.x + vy * wdv.y);
  if (lane == 0) { als2[gw] = s_s; ald2[gw] = s_d; }
}

// ---------------- GAT layer 2 aggregation (H=1): only active dsts ----------------
__global__ __launch_bounds__(256) void k_agg1(const __half2* __restrict__ xw2,
    const float* __restrict__ als2, const float* __restrict__ ald2,
    const int* __restrict__ startB, const int* __restrict__ degBv,
    const int* __restrict__ nodeOfC, const int* __restrict__ csrB,
    const float* __restrict__ bias, __half* __restrict__ out2c, int n){
  __shared__ float pshare[4][64];
  int c = (blockIdx.x * 256 + threadIdx.x) >> 6;
  int lane = threadIdx.x & 63;
  int ws = (threadIdx.x >> 6) & 3;
  if (c >= n) return;
  int e0  = __builtin_amdgcn_readfirstlane(startB[c]);
  int deg = __builtin_amdgcn_readfirstlane(degBv[c]);
  int e1 = e0 + deg;
  int dst = nodeOfC[c];
  float aldd = ald2[dst];
  int hid = lane >> 5;
  int cw = lane & 31;
  const float* myp = &pshare[ws][0] + hid;
  float den = 0.f, accx = 0.f, accy = 0.f;
  for (int base = e0; base < e1; base += 64) {
    int e = base + lane;
    bool valid = (e < e1);
    int srcv = valid ? csrB[e] : 0;
    float p = 0.f;
    if (valid) {
      float v = als2[srcv] + aldd;
      v = fmaxf(v, 0.2f * v);
      p = __expf(v);
    }
    den += p;
    pshare[ws][lane] = p;
    int cnt = min(e1 - base, 64);
    const int* cp = csrB + base;
    int j = 0;
    for (; j + 16 <= cnt; j += 16) gat1_blk<8>(cp, j, myp, xw2, cw, hid, accx, accy);
    if (j + 8 <= cnt) { gat1_blk<4>(cp, j, myp, xw2, cw, hid, accx, accy); j += 8; }
    if (j + 4 <= cnt) { gat1_blk<2>(cp, j, myp, xw2, cw, hid, accx, accy); j += 4; }
    for (; j < cnt; j += 2) gat1_blk<1>(cp, j, myp, xw2, cw, hid, accx, accy);
  }
  accx += __shfl_xor(accx, 32, 64);
  accy += __shfl_xor(accy, 32, 64);
  float dent = wsum64(den);
  if (lane < 32) {
    float inv = 1.f / (dent + 1e-16f);
    float2 b = *(const float2*)(bias + 2 * cw);
    float vx = accx * inv + b.x;
    float vy = accy * inv + b.y;
    *(__half2*)(out2c + (size_t)c * 64 + 2 * cw) = __floats2half2_rn(vx, vy);
  }
}

// ---------------- prediction head: register-tiled 64x64 GEMM, K=192 ----------------
__global__ __launch_bounds__(256) void k_head(const float* __restrict__ uemb,
    const int* __restrict__ uids,
    const __half* __restrict__ out2c, const float* __restrict__ pw1,
    const float* __restrict__ pb1, const float* __restrict__ pw2,
    const float* __restrict__ pb2, float* __restrict__ out, int B){
  __shared__ __align__(16) float As[64][196];
  __shared__ __align__(16) float Ws[192][64];
  int tid = threadIdx.x;
  for (int i = tid; i < 192 * 64 / 4; i += 256)
    ((float4*)&Ws[0][0])[i] = ((const float4*)pw1)[i];
  int w = tid >> 6, lane = tid & 63;
  int rbase = blockIdx.x * 64;
  for (int r = w; r < 64; r += 4) {
    int b = rbase + r;
    int uid = uids[b];
    As[r][lane]       = uemb[(size_t)uid * 64 + lane];
    As[r][64 + lane]  = __half2float(out2c[(size_t)(BB + b) * 64 + lane]);  // item row
    As[r][128 + lane] = __half2float(out2c[(size_t)b * 64 + lane]);        // user row
  }
  __syncthreads();
  int tm = (tid >> 4) * 4;
  int tn = (tid & 15) * 4;
  float acc[4][4];
#pragma unroll
  for (int i = 0; i < 4; i++)
#pragma unroll
    for (int j = 0; j < 4; j++) acc[i][j] = 0.f;
  for (int k = 0; k < 192; k += 4) {
    float4 a[4], wv[4];
#pragma unroll
    for (int i = 0; i < 4; i++) a[i] = *(const float4*)&As[tm + i][k];
#pragma unroll
    for (int q = 0; q < 4; q++) wv[q] = *(const float4*)&Ws[k + q][tn];
#pragma unroll
    for (int i = 0; i < 4; i++) {
      acc[i][0] = fmaf(a[i].x, wv[0].x, acc[i][0]);
      acc[i][1] = fmaf(a[i].x, wv[0].y, acc[i][1]);
      acc[i][2] = fmaf(a[i].x, wv[0].z, acc[i][2]);
      acc[i][3] = fmaf(a[i].x, wv[0].w, acc[i][3]);
      acc[i][0] = fmaf(a[i].y, wv[1].x, acc[i][0]);
      acc[i][1] = fmaf(a[i].y, wv[1].y, acc[i][1]);
      acc[i][2] = fmaf(a[i].y, wv[1].z, acc[i][2]);
      acc[i][3] = fmaf(a[i].y, wv[1].w, acc[i][3]);
      acc[i][0] = fmaf(a[i].z, wv[2].x, acc[i][0]);
      acc[i][1] = fmaf(a[i].z, wv[2].y, acc[i][1]);
      acc[i][2] = fmaf(a[i].z, wv[2].z, acc[i][2]);
      acc[i][3] = fmaf(a[i].z, wv[2].w, acc[i][3]);
      acc[i][0] = fmaf(a[i].w, wv[3].x, acc[i][0]);
      acc[i][1] = fmaf(a[i].w, wv[3].y, acc[i][1]);
      acc[i][2] = fmaf(a[i].w, wv[3].z, acc[i][2]);
      acc[i][3] = fmaf(a[i].w, wv[3].w, acc[i][3]);
    }
  }
  float4 pb1v = *(const float4*)(pb1 + tn);
  float4 pw2v = *(const float4*)(pw2 + tn);
  float pb2v = pb2[0];
#pragma unroll
  for (int i = 0; i < 4; i++) {
    float h0 = fmaxf(acc[i][0] + pb1v.x, 0.f);
    float h1 = fmaxf(acc[i][1] + pb1v.y, 0.f);
    float h2 = fmaxf(acc[i][2] + pb1v.z, 0.f);
    float h3 = fmaxf(acc[i][3] + pb1v.w, 0.f);
    float part = h0 * pw2v.x + h1 * pw2v.y + h2 * pw2v.z + h3 * pw2v.w;
#pragma unroll
    for (int d = 1; d < 16; d <<= 1) part += __shfl_xor(part, d, 64);
    if ((tid & 15) == 0) out[rbase + tm + i] = part + pb2v;
  }
}

// ---------------- launcher ----------------
extern "C" void kernel_launch(void* const* d_in, const int* in_sizes, int n_in,
                              void* d_out, int out_size, void* d_ws, size_t ws_size,
                              hipStream_t stream) {
  (void)in_sizes; (void)n_in; (void)out_size; (void)ws_size;
  const int*   user_ids = (const int*)  d_in[0];
  const int*   item_ids = (const int*)  d_in[1];
  const float* content  = (const float*)d_in[2];
  const int*   edge_idx = (const int*)  d_in[3];
  const float* uemb     = (const float*)d_in[4];
  const float* iemb     = (const float*)d_in[5];
  const float* cp_w     = (const float*)d_in[6];
  const float* cp_b     = (const float*)d_in[7];
  const float* w1       = (const float*)d_in[8];
  const float* asrc1    = (const float*)d_in[9];
  const float* adst1    = (const float*)d_in[10];
  const float* b1       = (const float*)d_in[11];
  const float* w2       = (const float*)d_in[12];
  const float* asrc2    = (const float*)d_in[13];
  const float* adst2    = (const float*)d_in[14];
  const float* b2       = (const float*)d_in[15];
  const float* pw1      = (const float*)d_in[16];
  const float* pb1      = (const float*)d_in[17];
  const float* pw2      = (const float*)d_in[18];
  const float* pb2      = (const float*)d_in[19];
  float* out = (float*)d_out;

  // ---- workspace layout (~101 MB) ----
  char* p = (char*)d_ws;
  // R0: bdata (k_bin/k_bucket) then reused as x1 (layer-1 output, full)
  int*    bdata = (int*)p;                       // [NBUK*CAP] = 19.2 MB
  __half* x1    = (__half*)p;                    // [ND,128] = 38.4 MB (after k_bucket)
  p += (size_t)ND * 128 * 2;
  __half* xc   = (__half*)p; p += (size_t)MACT * 128 * 2;   // compact input
  __half* xwc  = (__half*)p; p += (size_t)MACT * 128 * 2;   // compact xw1
  __half* xw2  = (__half*)p; p += (size_t)ND * 64 * 2;      // layer-2 xw (full)
  __half* out2c= (__half*)p; p += (size_t)MACT * 64 * 2;    // compact layer-2 out
  __half* Wt1  = (__half*)p; p += 16384 * 2;
  __half* Wt2  = (__half*)p; p += 8192 * 2;
  // zero-memset region: [ald1 | bitmap | bcnt | bcntA | bcntB]
  float* ald1     = (float*)p;
  unsigned* bitmap= (unsigned*)(ald1 + (size_t)ND * 2);
  int* bcnt       = (int*)(bitmap + NBMW);
  int* bcntA      = bcnt + NBUK;
  int* bcntB      = bcntA + NBUK;
  size_t zbytes   = (char*)(bcntB + NBUK) - (char*)ald1;
  p = (char*)(bcntB + NBUK);
  float* als1c = (float*)p; p += (size_t)MACT * 2 * 4;
  float* als2  = (float*)p; p += (size_t)ND * 4;
  float* ald2  = (float*)p; p += (size_t)ND * 4;
  int* flags   = (int*)p;   p += (size_t)ND * 4;            // memset 0xFF
  int* nodeOfC = (int*)p;   p += (size_t)MACT * 4;
  int* inactA  = (int*)p;   p += (size_t)ND * 4;
  int* offsA   = (int*)p;   p += (size_t)(ND + 16) * 4;
  int* startB  = (int*)p;   p += (size_t)MACT * 4;
  int* degBv   = (int*)p;   p += (size_t)MACT * 4;
  int* bbase   = (int*)p;   p += NBUK * 4;
  int* bbaseA  = (int*)p;   p += NBUK * 4;
  int* bbaseB  = (int*)p;   p += NBUK * 4;
  int* csrA    = (int*)p;   p += (size_t)(ETOT + 16) * 4;
  int* csrB    = (int*)p;   p += (size_t)(ETOT + 16) * 4;
  float* wa1s  = (float*)p; p += 256 * 4;
  float* wa1d  = (float*)p; p += 256 * 4;
  float* wa2s  = (float*)p; p += 128 * 4;
  float* wa2d  = (float*)p; p += 128 * 4;

  hipMemsetAsync(flags, 0xFF, (size_t)ND * 4, stream);
  hipMemsetAsync(ald1, 0, zbytes, stream);

  k_prep<<<97, 256, 0, stream>>>(w1, w2, Wt1, Wt2, asrc1, adst1, asrc2, adst2,
                                 wa1s, wa1d, wa2s, wa2d);

  k_scatter<<<NB_USERS + NB_ITEMS, 256, 0, stream>>>(user_ids, uemb, content, cp_w,
      cp_b, iemb, item_ids, xc, wa1s, wa1d, als1c, ald1, flags, bitmap, nodeOfC);

  // CSR build: bucket sort with activity filtering
  k_bin<<<NCH, 256, 0, stream>>>(edge_idx, bitmap, bcnt, bcntA, bcntB, bdata);
  k_bscan<<<1, 64, 0, stream>>>(bcnt, bbase, bcntA, bbaseA, bcntB, bbaseB,
                                offsA + ND, csrA, csrB);
  k_bucket<<<NBUK, 256, 0, stream>>>(bdata, bcnt, bbase, bbaseA, bbaseB, flags,
                                     offsA, inactA, startB, degBv, csrA, csrB);

  // ----- GAT layer 1 (H=2): compact GEMM + filtered aggregation -----
  k_mfma<8><<<(MACT + 127) / 128, 256, 0, stream>>>(xc, Wt1, xwc, MACT);
  k_agg2<<<((size_t)ND * 64 + 255) / 256, 256, 0, stream>>>((const __half2*)xwc,
      als1c, ald1, offsA, inactA, csrA, b1, x1, wa2s, wa2d, als2, ald2, ND);

  // ----- GAT layer 2 (H=1): full GEMM + active-dst aggregation -----
  k_mfma<4><<<(ND + 127) / 128, 256, 0, stream>>>(x1, Wt2, xw2, ND);
  k_agg1<<<(MACT * 64) / 256, 256, 0, stream>>>((const __half2*)xw2, als2, ald2,
      startB, degBv, nodeOfC, csrB, b2, out2c, MACT);

  // ----- head -----
  k_head<<<BB / 64, 256, 0, stream>>>(uemb, user_ids, out2c,
                                      pw1, pb1, pw2, pb2, out, BB);
}

// Round 9
// 376.424 us; speedup vs baseline: 1.5205x; 1.2309x over previous
//
#include <hip/hip_runtime.h>
#include <hip/hip_fp16.h>
#include <math.h>

// Problem constants (match reference)
static constexpr int ND  = 150000;   // total nodes
static constexpr int NUU = 100000;   // num users
static constexpr int BB  = 16384;    // batch
static constexpr int EE  = 2000000;  // edges (before self loops)
static constexpr int ETOT = EE + ND; // edges incl self loops
static constexpr int MACT = 2 * BB;  // active nodes (touched by batch)

// bucket sort params
static constexpr int NBUK  = (ND + 127) >> 7;          // 1172 buckets of 128 nodes
static constexpr int CAP   = 4096;                     // per-bucket capacity (avg ~1835)
static constexpr int CHUNK = 4096;
static constexpr int NCH   = (ETOT + CHUNK - 1) / CHUNK;  // 526
static constexpr int NBMW  = (ND + 31) / 32;           // bitmap words (4688)
static constexpr unsigned long long M21 = 0x1FFFFF;

typedef _Float16 h8 __attribute__((ext_vector_type(8)));
typedef float    f4 __attribute__((ext_vector_type(4)));

// ---------------- wave helpers ----------------
__device__ __forceinline__ float wsum64(float v){
#pragma unroll
  for (int d = 32; d > 0; d >>= 1) v += __shfl_xor(v, d, 64);
  return v;
}

// ---------------- prep: content projection (fp32 GEMM) + weight transpose + wa ----------------
// blocks [0,256): cemb = content @ cpw + cpb  (64x64 tile, K=256)
// blocks [256,352): Wt1/Wt2 fp16 transpose;  block 352: wa vectors
__global__ __launch_bounds__(256) void k_prep(const float* __restrict__ content,
    const float* __restrict__ cpw, const float* __restrict__ cpb,
    float* __restrict__ cemb,
    const float* __restrict__ w1, const float* __restrict__ w2,
    __half* __restrict__ Wt1, __half* __restrict__ Wt2,
    const float* __restrict__ asrc1, const float* __restrict__ adst1,
    const float* __restrict__ asrc2, const float* __restrict__ adst2,
    float* __restrict__ wa1s, float* __restrict__ wa1d,
    float* __restrict__ wa2s, float* __restrict__ wa2d){
  __shared__ __align__(16) float As[64 * 68];
  __shared__ __align__(16) float Ws[64 * 68];
  int tid = threadIdx.x;
  if (blockIdx.x < 256) {
    int m_base = blockIdx.x * 64;
    int tm = (tid >> 4) * 4, tn = (tid & 15) * 4;
    int lm = tid >> 2, lq = tid & 3;
    float acc[4][4];
#pragma unroll
    for (int i = 0; i < 4; i++)
#pragma unroll
      for (int j = 0; j < 4; j++) acc[i][j] = 0.f;
    for (int ks = 0; ks < 256; ks += 64) {
#pragma unroll
      for (int p = 0; p < 4; p++) {
        float4 v = *(const float4*)(content + (size_t)(m_base + lm) * 256 + ks + lq * 16 + p * 4);
        *(float4*)(As + lm * 68 + lq * 16 + p * 4) = v;
      }
#pragma unroll
      for (int p = 0; p < 4; p++) {
        int n4 = lq + p * 4;
        float4 v = *(const float4*)(cpw + (size_t)(ks + lm) * 64 + n4 * 4);
        *(float4*)(Ws + lm * 68 + n4 * 4) = v;
      }
      __syncthreads();
#pragma unroll
      for (int kk = 0; kk < 64; kk += 4) {
        float4 a[4], wv[4];
#pragma unroll
        for (int i = 0; i < 4; i++) a[i] = *(const float4*)(As + (tm + i) * 68 + kk);
#pragma unroll
        for (int q = 0; q < 4; q++) wv[q] = *(const float4*)(Ws + (kk + q) * 68 + tn);
#pragma unroll
        for (int i = 0; i < 4; i++) {
          acc[i][0] = fmaf(a[i].x, wv[0].x, acc[i][0]); acc[i][1] = fmaf(a[i].x, wv[0].y, acc[i][1]);
          acc[i][2] = fmaf(a[i].x, wv[0].z, acc[i][2]); acc[i][3] = fmaf(a[i].x, wv[0].w, acc[i][3]);
          acc[i][0] = fmaf(a[i].y, wv[1].x, acc[i][0]); acc[i][1] = fmaf(a[i].y, wv[1].y, acc[i][1]);
          acc[i][2] = fmaf(a[i].y, wv[1].z, acc[i][2]); acc[i][3] = fmaf(a[i].y, wv[1].w, acc[i][3]);
          acc[i][0] = fmaf(a[i].z, wv[2].x, acc[i][0]); acc[i][1] = fmaf(a[i].z, wv[2].y, acc[i][1]);
          acc[i][2] = fmaf(a[i].z, wv[2].z, acc[i][2]); acc[i][3] = fmaf(a[i].z, wv[2].w, acc[i][3]);
          acc[i][0] = fmaf(a[i].w, wv[3].x, acc[i][0]); acc[i][1] = fmaf(a[i].w, wv[3].y, acc[i][1]);
          acc[i][2] = fmaf(a[i].w, wv[3].z, acc[i][2]); acc[i][3] = fmaf(a[i].w, wv[3].w, acc[i][3]);
        }
      }
      __syncthreads();
    }
    float4 bias = *(const float4*)(cpb + tn);
#pragma unroll
    for (int i = 0; i < 4; i++) {
      float4 o = make_float4(acc[i][0] + bias.x, acc[i][1] + bias.y,
                             acc[i][2] + bias.z, acc[i][3] + bias.w);
      *(float4*)(cemb + (size_t)(m_base + tm + i) * 64 + tn) = o;
    }
  } else if (blockIdx.x < 352) {
    int t = (blockIdx.x - 256) * 256 + tid;
    if (t < 16384) {
      int n = t >> 7, k = t & 127;
      Wt1[t] = __float2half(w1[k * 128 + n]);
    } else {
      int u = t - 16384;
      int n = u >> 7, k = u & 127;
      Wt2[u] = __float2half(w2[k * 64 + n]);
    }
  } else if (tid < 128) {
    int k = tid;  // 0..127
    float s0 = 0.f, s1 = 0.f, d0 = 0.f, d1 = 0.f, s2 = 0.f, d2 = 0.f;
    for (int c = 0; c < 64; c++) {
      float wA = w1[k * 128 + c];
      float wB = w1[k * 128 + 64 + c];
      s0 = fmaf(wA, asrc1[c], s0);       d0 = fmaf(wA, adst1[c], d0);
      s1 = fmaf(wB, asrc1[64 + c], s1);  d1 = fmaf(wB, adst1[64 + c], d1);
      float wC = w2[k * 64 + c];
      s2 = fmaf(wC, asrc2[c], s2);       d2 = fmaf(wC, adst2[c], d2);
    }
    wa1s[k * 2] = s0; wa1s[k * 2 + 1] = s1;
    wa1d[k * 2] = d0; wa1d[k * 2 + 1] = d1;
    wa2s[k] = s2; wa2d[k] = d2;
  }
}

// ---------------- light scatter: one wave per row (users then items) ----------------
__global__ __launch_bounds__(256) void k_scatter(const int* __restrict__ uids,
    const float* __restrict__ uemb, const float* __restrict__ cemb,
    const float* __restrict__ iemb, const int* __restrict__ iids,
    __half* __restrict__ xc,
    const float* __restrict__ wa1s, const float* __restrict__ wa1d,
    float* __restrict__ als1c, float* __restrict__ ald1,
    int* __restrict__ flags, unsigned* __restrict__ bitmap,
    int* __restrict__ nodeOfC){
  int t = blockIdx.x * 256 + threadIdx.x;
  int r = t >> 6, c = t & 63;
  float2 ws = *(const float2*)(wa1s + 2 * c);
  float2 wd = *(const float2*)(wa1d + 2 * c);
  if (r < BB) {             // user row; compact idx = r
    int uid = uids[r];
    float u = uemb[(size_t)uid * 64 + c];
    xc[(size_t)r * 128 + c]      = __float2half(u);
    xc[(size_t)r * 128 + 64 + c] = __float2half(0.f);
    float s0 = wsum64(u * ws.x);
    float s1 = wsum64(u * ws.y);
    float d0 = wsum64(u * wd.x);
    float d1 = wsum64(u * wd.y);
    if (c == 0) {
      *(float2*)(als1c + (size_t)r * 2) = make_float2(s0, s1);
      *(float2*)(ald1 + (size_t)uid * 2) = make_float2(d0, d1);
      flags[uid] = r;
      nodeOfC[r] = uid;
      atomicOr(&bitmap[uid >> 5], 1u << (uid & 31));
    }
  } else {                  // item row; compact idx = r (= BB + b)
    int b = r - BB;
    int iid = iids[b];
    int node = NUU + iid;
    float lo = iemb[(size_t)iid * 64 + c];
    float hi = cemb[(size_t)b * 64 + c];
    xc[(size_t)r * 128 + c]      = __float2half(lo);
    xc[(size_t)r * 128 + 64 + c] = __float2half(hi);
    float2 wsH = *(const float2*)(wa1s + 128 + 2 * c);
    float2 wdH = *(const float2*)(wa1d + 128 + 2 * c);
    float s0 = wsum64(lo * ws.x + hi * wsH.x);
    float s1 = wsum64(lo * ws.y + hi * wsH.y);
    float d0 = wsum64(lo * wd.x + hi * wdH.x);
    float d1 = wsum64(lo * wd.y + hi * wdH.y);
    if (c == 0) {
      *(float2*)(als1c + (size_t)r * 2) = make_float2(s0, s1);
      *(float2*)(ald1 + (size_t)node * 2) = make_float2(d0, d1);
      flags[node] = r;
      nodeOfC[r] = node;
      atomicOr(&bitmap[node >> 5], 1u << (node & 31));
    }
  }
}

// ---------------- CSR build pass 1: bin edges, packed u64 histogram ----------------
// bdata entry = src | srcAct<<18 | dstAct<<19 | (dst&127)<<20
// bcnt64 fields: all @0, srcAct @21, dstAct @42
__global__ __launch_bounds__(256) void k_bin(const int* __restrict__ ei,
    const unsigned* __restrict__ bitmap, unsigned long long* __restrict__ bcnt64,
    int* __restrict__ bdata){
  __shared__ unsigned long long h64[NBUK];   // 9.4 KB
  __shared__ int base[NBUK];                 // 4.7 KB
  __shared__ int hist[NBUK];                 // 4.7 KB
  int tid = threadIdx.x;
  int t0 = blockIdx.x * CHUNK;
  for (int i = tid; i < NBUK; i += 256) h64[i] = 0ull;
  __syncthreads();
  for (int i = tid; i < CHUNK; i += 256) {
    int t = t0 + i;
    if (t >= ETOT) break;
    int src, dst;
    if (t < EE) { src = ei[t]; dst = ei[EE + t]; }
    else        { src = dst = t - EE; }
    unsigned long long sa = (bitmap[src >> 5] >> (src & 31)) & 1;
    unsigned long long da = (bitmap[dst >> 5] >> (dst & 31)) & 1;
    atomicAdd(&h64[dst >> 7], 1ull | (sa << 21) | (da << 42));
  }
  __syncthreads();
  for (int b = tid; b < NBUK; b += 256) {
    unsigned long long v = h64[b];
    base[b] = v ? (int)(atomicAdd(&bcnt64[b], v) & M21) : 0;
    hist[b] = 0;
  }
  __syncthreads();
  for (int i = tid; i < CHUNK; i += 256) {
    int t = t0 + i;
    if (t >= ETOT) break;
    int src, dst;
    if (t < EE) { src = ei[t]; dst = ei[EE + t]; }
    else        { src = dst = t - EE; }
    int sa = (bitmap[src >> 5] >> (src & 31)) & 1;
    int da = (bitmap[dst >> 5] >> (dst & 31)) & 1;
    int b = dst >> 7;
    int r = base[b] + atomicAdd(&hist[b], 1);
    if (r < CAP)
      bdata[(size_t)b * CAP + r] = src | (sa << 18) | (da << 19) | ((dst & 127) << 20);
  }
}

// ---------------- pass 2: fused 3-field bucket scan ----------------
__global__ void k_bscan(const unsigned long long* __restrict__ bcnt64,
    int* __restrict__ bbaseA, int* __restrict__ bbaseB,
    int* __restrict__ offsA_end, int* __restrict__ csrA, int* __restrict__ csrB){
  int lane = threadIdx.x;   // 64 threads
  int cA = 0, cB = 0;
  for (int c0 = 0; c0 < NBUK; c0 += 64) {
    int i = c0 + lane;
    unsigned long long v = (i < NBUK) ? bcnt64[i] : 0ull;
    int a = (int)((v >> 21) & M21);
    int b = (int)((v >> 42) & M21);
    int xa = a, xb = b;
#pragma unroll
    for (int d = 1; d < 64; d <<= 1) {
      int ta = __shfl_up(xa, d, 64); if (lane >= d) xa += ta;
      int tb = __shfl_up(xb, d, 64); if (lane >= d) xb += tb;
    }
    if (i < NBUK) { bbaseA[i] = cA + xa - a; bbaseB[i] = cB + xb - b; }
    cA += __shfl(xa, 63, 64);
    cB += __shfl(xb, 63, 64);
  }
  if (lane == 0) *offsA_end = cA;
  if (lane < 16) { csrA[cA + lane] = 0; csrB[cB + lane] = 0; }
}

// ---------------- pass 3: per-bucket scan + filtered scatter into csrA/csrB ----------------
__global__ __launch_bounds__(256) void k_bucket(const int* __restrict__ bdata,
    const unsigned long long* __restrict__ bcnt64,
    const int* __restrict__ bbaseA, const int* __restrict__ bbaseB,
    const int* __restrict__ flags,
    int* __restrict__ offsA, int* __restrict__ inactA,
    int* __restrict__ startB, int* __restrict__ degBv,
    int* __restrict__ csrA, int* __restrict__ csrB){
  __shared__ int degAll[128], degAct[128], curA[128], curB[128];
  int b = blockIdx.x;
  int tid = threadIdx.x;
  int cnt = (int)(bcnt64[b] & M21);
  const int* bd = bdata + (size_t)b * CAP;
  if (tid < 128) { degAll[tid] = 0; degAct[tid] = 0; }
  __syncthreads();
  for (int i = tid; i < cnt; i += 256) {
    int e = bd[i];
    int d7 = (e >> 20) & 127;
    atomicAdd(&degAll[d7], 1);
    if ((e >> 18) & 1) atomicAdd(&degAct[d7], 1);
  }
  __syncthreads();
  if (tid < 64) {
    int g0 = b * 128 + tid, g1 = g0 + 64;
    int A0 = degAll[tid], A1 = degAll[64 + tid];
    int a0 = degAct[tid], a1 = degAct[64 + tid];
    int s0 = a0, s1 = a1;
#pragma unroll
    for (int d = 1; d < 64; d <<= 1) {
      int t0 = __shfl_up(s0, d, 64); if (tid >= d) s0 += t0;
      int t1 = __shfl_up(s1, d, 64); if (tid >= d) s1 += t1;
    }
    int totA0 = __shfl(s0, 63, 64);
    int eA0 = s0 - a0, eA1 = s1 - a1 + totA0;
    int baseA = bbaseA[b];
    curA[tid] = baseA + eA0; curA[64 + tid] = baseA + eA1;
    if (g0 < ND) { offsA[g0] = baseA + eA0; inactA[g0] = A0 - a0; }
    if (g1 < ND) { offsA[g1] = baseA + eA1; inactA[g1] = A1 - a1; }
    int f0 = (g0 < ND) ? flags[g0] : -1;
    int f1 = (g1 < ND) ? flags[g1] : -1;
    int w0 = (f0 >= 0) ? A0 : 0, w1 = (f1 >= 0) ? A1 : 0;
    int t0 = w0, t1 = w1;
#pragma unroll
    for (int d = 1; d < 64; d <<= 1) {
      int u0 = __shfl_up(t0, d, 64); if (tid >= d) t0 += u0;
      int u1 = __shfl_up(t1, d, 64); if (tid >= d) t1 += u1;
    }
    int totB0 = __shfl(t0, 63, 64);
    int eB0 = t0 - w0, eB1 = t1 - w1 + totB0;
    int baseB = bbaseB[b];
    curB[tid] = baseB + eB0; curB[64 + tid] = baseB + eB1;
    if (f0 >= 0) { startB[f0] = baseB + eB0; degBv[f0] = A0; }
    if (f1 >= 0) { startB[f1] = baseB + eB1; degBv[f1] = A1; }
  }
  __syncthreads();
  for (int i = tid; i < cnt; i += 256) {
    int e = bd[i];
    int d7 = (e >> 20) & 127;
    int src = e & 0x3FFFF;
    if ((e >> 19) & 1) { int p = atomicAdd(&curB[d7], 1); csrB[p] = src; }
    if ((e >> 18) & 1) {
      int ci = flags[src];
      int p = atomicAdd(&curA[d7], 1);
      csrA[p] = ci;                      // store compact idx directly
    }
  }
}

// ---------------- MFMA fp16 GEMM: C[M,N](f16) = A[M,128](f16) @ Bt[N,128]^T ----------------
template<int NT>   // N = NT*16
__global__ __launch_bounds__(256) void k_mfma(const __half* __restrict__ A,
    const __half* __restrict__ Bt, __half* __restrict__ C, int M){
  constexpr int N = NT * 16;
  int wid  = (blockIdx.x * 256 + threadIdx.x) >> 6;
  int lane = threadIdx.x & 63;
  int q = lane >> 4, mr = lane & 15;
  int r0 = wid * 32;
  if (r0 >= M) return;
  int row0 = min(r0 + mr, M - 1);
  int row1 = min(r0 + 16 + mr, M - 1);
  f4 acc[2][NT];
#pragma unroll
  for (int i = 0; i < 2; i++)
#pragma unroll
    for (int j = 0; j < NT; j++) acc[i][j] = (f4)0.f;
#pragma unroll
  for (int ks = 0; ks < 4; ks++) {
    int ko = ks * 32 + q * 8;
    h8 a0 = *(const h8*)(A + (size_t)row0 * 128 + ko);
    h8 a1 = *(const h8*)(A + (size_t)row1 * 128 + ko);
#pragma unroll
    for (int nt = 0; nt < NT; nt++) {
      h8 b = *(const h8*)(Bt + (size_t)(nt * 16 + mr) * 128 + ko);
      acc[0][nt] = __builtin_amdgcn_mfma_f32_16x16x32_f16(a0, b, acc[0][nt], 0, 0, 0);
      acc[1][nt] = __builtin_amdgcn_mfma_f32_16x16x32_f16(a1, b, acc[1][nt], 0, 0, 0);
    }
  }
#pragma unroll
  for (int mt = 0; mt < 2; mt++)
#pragma unroll
    for (int r = 0; r < 4; r++) {
      int row = r0 + mt * 16 + q * 4 + r;
      if (row < M) {
#pragma unroll
        for (int nt = 0; nt < NT; nt++)
          C[(size_t)row * N + nt * 16 + mr] = __float2half(acc[mt][nt][r]);
      }
    }
}

// ---------------- gather blocks ----------------
template<int U>
__device__ __forceinline__ void gat2_blk(const int* __restrict__ cp, int j0,
    const float* __restrict__ myp, const __half2* __restrict__ xw, int lane,
    float& accx, float& accy){
  __half2 hv[U]; float pj[U];
#pragma unroll
  for (int u = 0; u < U; u++) {
    int sj = __builtin_amdgcn_readfirstlane(cp[j0 + u]);
    hv[u] = xw[(size_t)sj * 64 + lane];
    pj[u] = myp[j0 + u];
  }
#pragma unroll
  for (int u = 0; u < U; u++) {
    float2 fv = __half22float2(hv[u]);
    accx = fmaf(pj[u], fv.x, accx);
    accy = fmaf(pj[u], fv.y, accy);
  }
}

template<int U>   // U pairs = 2U edges
__device__ __forceinline__ void gat1_blk(const int* __restrict__ cp, int j0,
    const float* __restrict__ myp, const __half2* __restrict__ xw, int cw, int hid,
    float& accx, float& accy){
  __half2 hv[U]; float pj[U];
#pragma unroll
  for (int u = 0; u < U; u++) {
    int j = j0 + 2 * u;
    int s0 = __builtin_amdgcn_readfirstlane(cp[j]);
    int s1 = __builtin_amdgcn_readfirstlane(cp[j + 1]);
    int sel = hid ? s1 : s0;
    hv[u] = xw[(size_t)sel * 32 + cw];
    pj[u] = myp[j];
  }
#pragma unroll
  for (int u = 0; u < U; u++) {
    float2 fv = __half22float2(hv[u]);
    accx = fmaf(pj[u], fv.x, accx);
    accy = fmaf(pj[u], fv.y, accy);
  }
}

// ---------------- GAT layer 1 aggregation (H=2), filtered csrA ----------------
__global__ __launch_bounds__(256) void k_agg2(const __half2* __restrict__ xwc,
    const float* __restrict__ als1c, const float* __restrict__ ald1,
    const int* __restrict__ offsA, const int* __restrict__ inactA,
    const int* __restrict__ csrA,
    const float* __restrict__ bias, __half* __restrict__ out,
    const float* __restrict__ wa2s, const float* __restrict__ wa2d,
    float* __restrict__ als2, float* __restrict__ ald2, int n){
  __shared__ float pshare[4][2][64];
  int gw = (blockIdx.x * 256 + threadIdx.x) >> 6;
  int lane = threadIdx.x & 63;
  int ws = (threadIdx.x >> 6) & 3;
  if (gw >= n) return;
  int e0 = __builtin_amdgcn_readfirstlane(offsA[gw]);
  int e1 = __builtin_amdgcn_readfirstlane(offsA[gw + 1]);
  int inact = __builtin_amdgcn_readfirstlane(inactA[gw]);
  float2 aldv = *(const float2*)(ald1 + (size_t)gw * 2);
  bool lo = lane < 32;
  const float* myp = &pshare[ws][0][0] + (lo ? 0 : 64);
  float den0 = 0.f, den1 = 0.f, accx = 0.f, accy = 0.f;
  for (int base = e0; base < e1; base += 64) {
    int e = base + lane;
    bool valid = (e < e1);
    int srcv = valid ? csrA[e] : 0;
    float p0 = 0.f, p1 = 0.f;
    if (valid) {
      float2 a = *(const float2*)(als1c + (size_t)srcv * 2);
      float v0 = a.x + aldv.x, v1 = a.y + aldv.y;
      v0 = fmaxf(v0, 0.2f * v0);
      v1 = fmaxf(v1, 0.2f * v1);
      p0 = __expf(v0); p1 = __expf(v1);
    }
    den0 += p0; den1 += p1;
    pshare[ws][0][lane] = p0;
    pshare[ws][1][lane] = p1;
    int cnt = min(e1 - base, 64);
    const int* cp = csrA + base;
    int j = 0;
    for (; j + 16 <= cnt; j += 16) gat2_blk<16>(cp, j, myp, xwc, lane, accx, accy);
    if (j + 8 <= cnt) { gat2_blk<8>(cp, j, myp, xwc, lane, accx, accy); j += 8; }
    if (j + 4 <= cnt) { gat2_blk<4>(cp, j, myp, xwc, lane, accx, accy); j += 4; }
    if (j + 2 <= cnt) { gat2_blk<2>(cp, j, myp, xwc, lane, accx, accy); j += 2; }
    if (j < cnt)        gat2_blk<1>(cp, j, myp, xwc, lane, accx, accy);
  }
  float pin0 = __expf(fmaxf(aldv.x, 0.2f * aldv.x));
  float pin1 = __expf(fmaxf(aldv.y, 0.2f * aldv.y));
  float dt0 = wsum64(den0) + (float)inact * pin0;
  float dt1 = wsum64(den1) + (float)inact * pin1;
  float den = (lo ? dt0 : dt1) + 1e-16f;
  float inv = 1.f / den;
  float2 b = *(const float2*)(bias + 2 * lane);
  float vx = accx * inv + b.x;
  float vy = accy * inv + b.y;
  vx = (vx > 0.f) ? vx : expm1f(vx);         // elu
  vy = (vy > 0.f) ? vy : expm1f(vy);
  *(__half2*)(out + (size_t)gw * 128 + 2 * lane) = __floats2half2_rn(vx, vy);
  float2 wsv = *(const float2*)(wa2s + 2 * lane);
  float2 wdv = *(const float2*)(wa2d + 2 * lane);
  float s_s = wsum64(vx * wsv.x + vy * wsv.y);
  float s_d = wsum64(vx * wdv.x + vy * wdv.y);
  if (lane == 0) { als2[gw] = s_s; ald2[gw] = s_d; }
}

// ---------------- GAT layer 2 aggregation (H=1): only active dsts ----------------
__global__ __launch_bounds__(256) void k_agg1(const __half2* __restrict__ xw2,
    const float* __restrict__ als2, const float* __restrict__ ald2,
    const int* __restrict__ startB, const int* __restrict__ degBv,
    const int* __restrict__ nodeOfC, const int* __restrict__ csrB,
    const float* __restrict__ bias, __half* __restrict__ out2c, int n){
  __shared__ float pshare[4][64];
  int c = (blockIdx.x * 256 + threadIdx.x) >> 6;
  int lane = threadIdx.x & 63;
  int ws = (threadIdx.x >> 6) & 3;
  if (c >= n) return;
  int e0  = __builtin_amdgcn_readfirstlane(startB[c]);
  int deg = __builtin_amdgcn_readfirstlane(degBv[c]);
  int e1 = e0 + deg;
  int dst = nodeOfC[c];
  float aldd = ald2[dst];
  int hid = lane >> 5;
  int cw = lane & 31;
  const float* myp = &pshare[ws][0] + hid;
  float den = 0.f, accx = 0.f, accy = 0.f;
  for (int base = e0; base < e1; base += 64) {
    int e = base + lane;
    bool valid = (e < e1);
    int srcv = valid ? csrB[e] : 0;
    float p = 0.f;
    if (valid) {
      float v = als2[srcv] + aldd;
      v = fmaxf(v, 0.2f * v);
      p = __expf(v);
    }
    den += p;
    pshare[ws][lane] = p;
    int cnt = min(e1 - base, 64);
    const int* cp = csrB + base;
    int j = 0;
    for (; j + 16 <= cnt; j += 16) gat1_blk<8>(cp, j, myp, xw2, cw, hid, accx, accy);
    if (j + 8 <= cnt) { gat1_blk<4>(cp, j, myp, xw2, cw, hid, accx, accy); j += 8; }
    if (j + 4 <= cnt) { gat1_blk<2>(cp, j, myp, xw2, cw, hid, accx, accy); j += 4; }
    for (; j < cnt; j += 2) gat1_blk<1>(cp, j, myp, xw2, cw, hid, accx, accy);
  }
  accx += __shfl_xor(accx, 32, 64);
  accy += __shfl_xor(accy, 32, 64);
  float dent = wsum64(den);
  if (lane < 32) {
    float inv = 1.f / (dent + 1e-16f);
    float2 b = *(const float2*)(bias + 2 * cw);
    float vx = accx * inv + b.x;
    float vy = accy * inv + b.y;
    *(__half2*)(out2c + (size_t)c * 64 + 2 * cw) = __floats2half2_rn(vx, vy);
  }
}

// ---------------- prediction head: register-tiled 64x64 GEMM, K=192 ----------------
__global__ __launch_bounds__(256) void k_head(const float* __restrict__ uemb,
    const int* __restrict__ uids,
    const __half* __restrict__ out2c, const float* __restrict__ pw1,
    const float* __restrict__ pb1, const float* __restrict__ pw2,
    const float* __restrict__ pb2, float* __restrict__ out, int B){
  __shared__ __align__(16) float As[64][196];
  __shared__ __align__(16) float Ws[192][64];
  int tid = threadIdx.x;
  for (int i = tid; i < 192 * 64 / 4; i += 256)
    ((float4*)&Ws[0][0])[i] = ((const float4*)pw1)[i];
  int w = tid >> 6, lane = tid & 63;
  int rbase = blockIdx.x * 64;
  for (int r = w; r < 64; r += 4) {
    int b = rbase + r;
    int uid = uids[b];
    As[r][lane]       = uemb[(size_t)uid * 64 + lane];
    As[r][64 + lane]  = __half2float(out2c[(size_t)(BB + b) * 64 + lane]);  // item row
    As[r][128 + lane] = __half2float(out2c[(size_t)b * 64 + lane]);        // user row
  }
  __syncthreads();
  int tm = (tid >> 4) * 4;
  int tn = (tid & 15) * 4;
  float acc[4][4];
#pragma unroll
  for (int i = 0; i < 4; i++)
#pragma unroll
    for (int j = 0; j < 4; j++) acc[i][j] = 0.f;
  for (int k = 0; k < 192; k += 4) {
    float4 a[4], wv[4];
#pragma unroll
    for (int i = 0; i < 4; i++) a[i] = *(const float4*)&As[tm + i][k];
#pragma unroll
    for (int q = 0; q < 4; q++) wv[q] = *(const float4*)&Ws[k + q][tn];
#pragma unroll
    for (int i = 0; i < 4; i++) {
      acc[i][0] = fmaf(a[i].x, wv[0].x, acc[i][0]); acc[i][1] = fmaf(a[i].x, wv[0].y, acc[i][1]);
      acc[i][2] = fmaf(a[i].x, wv[0].z, acc[i][2]); acc[i][3] = fmaf(a[i].x, wv[0].w, acc[i][3]);
      acc[i][0] = fmaf(a[i].y, wv[1].x, acc[i][0]); acc[i][1] = fmaf(a[i].y, wv[1].y, acc[i][1]);
      acc[i][2] = fmaf(a[i].y, wv[1].z, acc[i][2]); acc[i][3] = fmaf(a[i].y, wv[1].w, acc[i][3]);
      acc[i][0] = fmaf(a[i].z, wv[2].x, acc[i][0]); acc[i][1] = fmaf(a[i].z, wv[2].y, acc[i][1]);
      acc[i][2] = fmaf(a[i].z, wv[2].z, acc[i][2]); acc[i][3] = fmaf(a[i].z, wv[2].w, acc[i][3]);
      acc[i][0] = fmaf(a[i].w, wv[3].x, acc[i][0]); acc[i][1] = fmaf(a[i].w, wv[3].y, acc[i][1]);
      acc[i][2] = fmaf(a[i].w, wv[3].z, acc[i][2]); acc[i][3] = fmaf(a[i].w, wv[3].w, acc[i][3]);
    }
  }
  float4 pb1v = *(const float4*)(pb1 + tn);
  float4 pw2v = *(const float4*)(pw2 + tn);
  float pb2v = pb2[0];
#pragma unroll
  for (int i = 0; i < 4; i++) {
    float h0 = fmaxf(acc[i][0] + pb1v.x, 0.f);
    float h1 = fmaxf(acc[i][1] + pb1v.y, 0.f);
    float h2 = fmaxf(acc[i][2] + pb1v.z, 0.f);
    float h3 = fmaxf(acc[i][3] + pb1v.w, 0.f);
    float part = h0 * pw2v.x + h1 * pw2v.y + h2 * pw2v.z + h3 * pw2v.w;
#pragma unroll
    for (int d = 1; d < 16; d <<= 1) part += __shfl_xor(part, d, 64);
    if ((tid & 15) == 0) out[rbase + tm + i] = part + pb2v;
  }
}

// ---------------- launcher ----------------
extern "C" void kernel_launch(void* const* d_in, const int* in_sizes, int n_in,
                              void* d_out, int out_size, void* d_ws, size_t ws_size,
                              hipStream_t stream) {
  (void)in_sizes; (void)n_in; (void)out_size; (void)ws_size;
  const int*   user_ids = (const int*)  d_in[0];
  const int*   item_ids = (const int*)  d_in[1];
  const float* content  = (const float*)d_in[2];
  const int*   edge_idx = (const int*)  d_in[3];
  const float* uemb     = (const float*)d_in[4];
  const float* iemb     = (const float*)d_in[5];
  const float* cp_w     = (const float*)d_in[6];
  const float* cp_b     = (const float*)d_in[7];
  const float* w1       = (const float*)d_in[8];
  const float* asrc1    = (const float*)d_in[9];
  const float* adst1    = (const float*)d_in[10];
  const float* b1       = (const float*)d_in[11];
  const float* w2       = (const float*)d_in[12];
  const float* asrc2    = (const float*)d_in[13];
  const float* adst2    = (const float*)d_in[14];
  const float* b2       = (const float*)d_in[15];
  const float* pw1      = (const float*)d_in[16];
  const float* pb1      = (const float*)d_in[17];
  const float* pw2      = (const float*)d_in[18];
  const float* pb2      = (const float*)d_in[19];
  float* out = (float*)d_out;

  // ---- workspace layout (~107 MB) ----
  char* p = (char*)d_ws;
  // R0: bdata (k_bin/k_bucket) then reused as x1 (layer-1 output, full)
  int*    bdata = (int*)p;                       // [NBUK*CAP] = 19.2 MB
  __half* x1    = (__half*)p;                    // [ND,128] = 38.4 MB (after k_bucket)
  p += (size_t)ND * 128 * 2;
  __half* xc   = (__half*)p; p += (size_t)MACT * 128 * 2;   // compact input
  __half* xwc  = (__half*)p; p += (size_t)MACT * 128 * 2;   // compact xw1
  __half* xw2  = (__half*)p; p += (size_t)ND * 64 * 2;      // layer-2 xw (full)
  __half* out2c= (__half*)p; p += (size_t)MACT * 64 * 2;    // compact layer-2 out
  float* cemb  = (float*)p;  p += (size_t)BB * 64 * 4;      // content projection
  __half* Wt1  = (__half*)p; p += 16384 * 2;
  __half* Wt2  = (__half*)p; p += 8192 * 2;
  // zero-memset region: [ald1 | bitmap | bcnt64]
  float* ald1     = (float*)p;
  unsigned* bitmap= (unsigned*)(ald1 + (size_t)ND * 2);
  unsigned long long* bcnt64 = (unsigned long long*)(bitmap + NBMW);
  size_t zbytes   = (char*)(bcnt64 + NBUK) - (char*)ald1;
  p = (char*)(bcnt64 + NBUK);
  float* als1c = (float*)p; p += (size_t)MACT * 2 * 4;
  float* als2  = (float*)p; p += (size_t)ND * 4;
  float* ald2  = (float*)p; p += (size_t)ND * 4;
  int* flags   = (int*)p;   p += (size_t)ND * 4;            // memset 0xFF
  int* nodeOfC = (int*)p;   p += (size_t)MACT * 4;
  int* inactA  = (int*)p;   p += (size_t)ND * 4;
  int* offsA   = (int*)p;   p += (size_t)(ND + 16) * 4;
  int* startB  = (int*)p;   p += (size_t)MACT * 4;
  int* degBv   = (int*)p;   p += (size_t)MACT * 4;
  int* bbaseA  = (int*)p;   p += NBUK * 4;
  int* bbaseB  = (int*)p;   p += NBUK * 4;
  int* csrA    = (int*)p;   p += (size_t)(ETOT + 16) * 4;
  int* csrB    = (int*)p;   p += (size_t)(ETOT + 16) * 4;
  float* wa1s  = (float*)p; p += 256 * 4;
  float* wa1d  = (float*)p; p += 256 * 4;
  float* wa2s  = (float*)p; p += 128 * 4;
  float* wa2d  = (float*)p; p += 128 * 4;

  hipMemsetAsync(flags, 0xFF, (size_t)ND * 4, stream);
  hipMemsetAsync(ald1, 0, zbytes, stream);

  k_prep<<<353, 256, 0, stream>>>(content, cp_w, cp_b, cemb, w1, w2, Wt1, Wt2,
                                  asrc1, adst1, asrc2, adst2,
                                  wa1s, wa1d, wa2s, wa2d);

  k_scatter<<<MACT * 64 / 256, 256, 0, stream>>>(user_ids, uemb, cemb, iemb, item_ids,
      xc, wa1s, wa1d, als1c, ald1, flags, bitmap, nodeOfC);

  // CSR build: bucket sort with activity filtering
  k_bin<<<NCH, 256, 0, stream>>>(edge_idx, bitmap, bcnt64, bdata);
  k_bscan<<<1, 64, 0, stream>>>(bcnt64, bbaseA, bbaseB, offsA + ND, csrA, csrB);
  k_bucket<<<NBUK, 256, 0, stream>>>(bdata, bcnt64, bbaseA, bbaseB, flags,
                                     offsA, inactA, startB, degBv, csrA, csrB);

  // ----- GAT layer 1 (H=2): compact GEMM + filtered aggregation -----
  k_mfma<8><<<(MACT + 127) / 128, 256, 0, stream>>>(xc, Wt1, xwc, MACT);
  k_agg2<<<((size_t)ND * 64 + 255) / 256, 256, 0, stream>>>((const __half2*)xwc,
      als1c, ald1, offsA, inactA, csrA, b1, x1, wa2s, wa2d, als2, ald2, ND);

  // ----- GAT layer 2 (H=1): full GEMM + active-dst aggregation -----
  k_mfma<4><<<(ND + 127) / 128, 256, 0, stream>>>(x1, Wt2, xw2, ND);
  k_agg1<<<(MACT * 64) / 256, 256, 0, stream>>>((const __half2*)xw2, als2, ald2,
      startB, degBv, nodeOfC, csrB, b2, out2c, MACT);

  // ----- head -----
  k_head<<<BB / 64, 256, 0, stream>>>(uemb, user_ids, out2c,
                                      pw1, pb1, pw2, pb2, out, BB);
}

// Round 10
// 323.165 us; speedup vs baseline: 1.7710x; 1.1648x over previous
//
#include <hip/hip_runtime.h>
#include <hip/hip_fp16.h>
#include <math.h>

// Problem constants (match reference)
static constexpr int ND  = 150000;   // total nodes
static constexpr int NUU = 100000;   // num users
static constexpr int BB  = 16384;    // batch
static constexpr int EE  = 2000000;  // edges (before self loops)
static constexpr int ETOT = EE + ND; // edges incl self loops
static constexpr int MACT = 2 * BB;  // active nodes (touched by batch)

// bucket sort params
static constexpr int NBUK  = (ND + 127) >> 7;          // 1172 buckets of 128 nodes
static constexpr int CAP   = 4096;                     // per-bucket capacity (avg ~1835)
static constexpr int CHUNK = 4096;
static constexpr int NCH   = (ETOT + CHUNK - 1) / CHUNK;  // 526
static constexpr int NBMW  = (ND + 31) / 32;           // bitmap words (4688)
static constexpr unsigned long long M21 = 0x1FFFFF;

// zero/fill sizes for k_prep housekeeping (uint4 counts)
static constexpr int ZU4 = (ND * 8 + NBMW * 4 + NBUK * 8) / 16;  // 76758
static constexpr int FU4 = ND * 4 / 16;                          // 37500

typedef _Float16 h8 __attribute__((ext_vector_type(8)));
typedef float    f4 __attribute__((ext_vector_type(4)));

// ---------------- wave helpers ----------------
__device__ __forceinline__ float wsum64(float v){
#pragma unroll
  for (int d = 32; d > 0; d >>= 1) v += __shfl_xor(v, d, 64);
  return v;
}

// ---------------- prep: content GEMM + weight transpose + wa + ws housekeeping ----------------
// blocks [0,256): cemb = content @ cpw + cpb  (64x64 tile, K=256)
// [256,352): Wt1/Wt2 fp16 transpose;  352: wa vectors
// [353,393): zero [ald1|bitmap|bcnt64];  [393,409): flags = -1
__global__ __launch_bounds__(256) void k_prep(const float* __restrict__ content,
    const float* __restrict__ cpw, const float* __restrict__ cpb,
    float* __restrict__ cemb,
    const float* __restrict__ w1, const float* __restrict__ w2,
    __half* __restrict__ Wt1, __half* __restrict__ Wt2,
    const float* __restrict__ asrc1, const float* __restrict__ adst1,
    const float* __restrict__ asrc2, const float* __restrict__ adst2,
    float* __restrict__ wa1s, float* __restrict__ wa1d,
    float* __restrict__ wa2s, float* __restrict__ wa2d,
    uint4* __restrict__ zbase, uint4* __restrict__ fbase){
  __shared__ __align__(16) float As[64 * 68];
  __shared__ __align__(16) float Ws[64 * 68];
  int tid = threadIdx.x;
  if (blockIdx.x < 256) {
    int m_base = blockIdx.x * 64;
    int tm = (tid >> 4) * 4, tn = (tid & 15) * 4;
    int lm = tid >> 2, lq = tid & 3;
    float acc[4][4];
#pragma unroll
    for (int i = 0; i < 4; i++)
#pragma unroll
      for (int j = 0; j < 4; j++) acc[i][j] = 0.f;
    for (int ks = 0; ks < 256; ks += 64) {
#pragma unroll
      for (int p = 0; p < 4; p++) {
        float4 v = *(const float4*)(content + (size_t)(m_base + lm) * 256 + ks + lq * 16 + p * 4);
        *(float4*)(As + lm * 68 + lq * 16 + p * 4) = v;
      }
#pragma unroll
      for (int p = 0; p < 4; p++) {
        int n4 = lq + p * 4;
        float4 v = *(const float4*)(cpw + (size_t)(ks + lm) * 64 + n4 * 4);
        *(float4*)(Ws + lm * 68 + n4 * 4) = v;
      }
      __syncthreads();
#pragma unroll
      for (int kk = 0; kk < 64; kk += 4) {
        float4 a[4], wv[4];
#pragma unroll
        for (int i = 0; i < 4; i++) a[i] = *(const float4*)(As + (tm + i) * 68 + kk);
#pragma unroll
        for (int q = 0; q < 4; q++) wv[q] = *(const float4*)(Ws + (kk + q) * 68 + tn);
#pragma unroll
        for (int i = 0; i < 4; i++) {
          acc[i][0] = fmaf(a[i].x, wv[0].x, acc[i][0]); acc[i][1] = fmaf(a[i].x, wv[0].y, acc[i][1]);
          acc[i][2] = fmaf(a[i].x, wv[0].z, acc[i][2]); acc[i][3] = fmaf(a[i].x, wv[0].w, acc[i][3]);
          acc[i][0] = fmaf(a[i].y, wv[1].x, acc[i][0]); acc[i][1] = fmaf(a[i].y, wv[1].y, acc[i][1]);
          acc[i][2] = fmaf(a[i].y, wv[1].z, acc[i][2]); acc[i][3] = fmaf(a[i].y, wv[1].w, acc[i][3]);
          acc[i][0] = fmaf(a[i].z, wv[2].x, acc[i][0]); acc[i][1] = fmaf(a[i].z, wv[2].y, acc[i][1]);
          acc[i][2] = fmaf(a[i].z, wv[2].z, acc[i][2]); acc[i][3] = fmaf(a[i].z, wv[2].w, acc[i][3]);
          acc[i][0] = fmaf(a[i].w, wv[3].x, acc[i][0]); acc[i][1] = fmaf(a[i].w, wv[3].y, acc[i][1]);
          acc[i][2] = fmaf(a[i].w, wv[3].z, acc[i][2]); acc[i][3] = fmaf(a[i].w, wv[3].w, acc[i][3]);
        }
      }
      __syncthreads();
    }
    float4 bias = *(const float4*)(cpb + tn);
#pragma unroll
    for (int i = 0; i < 4; i++) {
      float4 o = make_float4(acc[i][0] + bias.x, acc[i][1] + bias.y,
                             acc[i][2] + bias.z, acc[i][3] + bias.w);
      *(float4*)(cemb + (size_t)(m_base + tm + i) * 64 + tn) = o;
    }
  } else if (blockIdx.x < 352) {
    int t = (blockIdx.x - 256) * 256 + tid;
    if (t < 16384) {
      int n = t >> 7, k = t & 127;
      Wt1[t] = __float2half(w1[k * 128 + n]);
    } else {
      int u = t - 16384;
      int n = u >> 7, k = u & 127;
      Wt2[u] = __float2half(w2[k * 64 + n]);
    }
  } else if (blockIdx.x == 352) {
    if (tid < 128) {
      int k = tid;  // 0..127
      float s0 = 0.f, s1 = 0.f, d0 = 0.f, d1 = 0.f, s2 = 0.f, d2 = 0.f;
      for (int c = 0; c < 64; c++) {
        float wA = w1[k * 128 + c];
        float wB = w1[k * 128 + 64 + c];
        s0 = fmaf(wA, asrc1[c], s0);       d0 = fmaf(wA, adst1[c], d0);
        s1 = fmaf(wB, asrc1[64 + c], s1);  d1 = fmaf(wB, adst1[64 + c], d1);
        float wC = w2[k * 64 + c];
        s2 = fmaf(wC, asrc2[c], s2);       d2 = fmaf(wC, adst2[c], d2);
      }
      wa1s[k * 2] = s0; wa1s[k * 2 + 1] = s1;
      wa1d[k * 2] = d0; wa1d[k * 2 + 1] = d1;
      wa2s[k] = s2; wa2d[k] = d2;
    }
  } else if (blockIdx.x < 393) {
    uint4 zv = make_uint4(0, 0, 0, 0);
    for (int i = (blockIdx.x - 353) * 256 + tid; i < ZU4; i += 40 * 256) zbase[i] = zv;
  } else {
    uint4 fv = make_uint4(~0u, ~0u, ~0u, ~0u);
    for (int i = (blockIdx.x - 393) * 256 + tid; i < FU4; i += 16 * 256) fbase[i] = fv;
  }
}

// ---------------- light scatter: one wave per row (users then items) ----------------
__global__ __launch_bounds__(256) void k_scatter(const int* __restrict__ uids,
    const float* __restrict__ uemb, const float* __restrict__ cemb,
    const float* __restrict__ iemb, const int* __restrict__ iids,
    __half* __restrict__ xc,
    const float* __restrict__ wa1s, const float* __restrict__ wa1d,
    float* __restrict__ als1c, float* __restrict__ ald1,
    int* __restrict__ flags, unsigned* __restrict__ bitmap,
    int* __restrict__ nodeOfC){
  int t = blockIdx.x * 256 + threadIdx.x;
  int r = t >> 6, c = t & 63;
  float2 ws = *(const float2*)(wa1s + 2 * c);
  float2 wd = *(const float2*)(wa1d + 2 * c);
  if (r < BB) {             // user row; compact idx = r
    int uid = uids[r];
    float u = uemb[(size_t)uid * 64 + c];
    xc[(size_t)r * 128 + c]      = __float2half(u);
    xc[(size_t)r * 128 + 64 + c] = __float2half(0.f);
    float s0 = wsum64(u * ws.x);
    float s1 = wsum64(u * ws.y);
    float d0 = wsum64(u * wd.x);
    float d1 = wsum64(u * wd.y);
    if (c == 0) {
      *(float2*)(als1c + (size_t)r * 2) = make_float2(s0, s1);
      *(float2*)(ald1 + (size_t)uid * 2) = make_float2(d0, d1);
      flags[uid] = r;
      nodeOfC[r] = uid;
      atomicOr(&bitmap[uid >> 5], 1u << (uid & 31));
    }
  } else {                  // item row; compact idx = r (= BB + b)
    int b = r - BB;
    int iid = iids[b];
    int node = NUU + iid;
    float lo = iemb[(size_t)iid * 64 + c];
    float hi = cemb[(size_t)b * 64 + c];
    xc[(size_t)r * 128 + c]      = __float2half(lo);
    xc[(size_t)r * 128 + 64 + c] = __float2half(hi);
    float2 wsH = *(const float2*)(wa1s + 128 + 2 * c);
    float2 wdH = *(const float2*)(wa1d + 128 + 2 * c);
    float s0 = wsum64(lo * ws.x + hi * wsH.x);
    float s1 = wsum64(lo * ws.y + hi * wsH.y);
    float d0 = wsum64(lo * wd.x + hi * wdH.x);
    float d1 = wsum64(lo * wd.y + hi * wdH.y);
    if (c == 0) {
      *(float2*)(als1c + (size_t)r * 2) = make_float2(s0, s1);
      *(float2*)(ald1 + (size_t)node * 2) = make_float2(d0, d1);
      flags[node] = r;
      nodeOfC[r] = node;
      atomicOr(&bitmap[node >> 5], 1u << (node & 31));
    }
  }
}

// ---------------- CSR build pass 1: single-pass bin with rank capture ----------------
// bdata entry = src | srcAct<<18 | dstAct<<19 | (dst&127)<<20
// bcnt64/h64 fields: all @0, srcAct @21, dstAct @42; rank from counting atomic.
__global__ __launch_bounds__(256) void k_bin(const int* __restrict__ ei,
    const unsigned* __restrict__ bitmap, unsigned long long* __restrict__ bcnt64,
    int* __restrict__ bdata){
  __shared__ unsigned long long h64[NBUK];   // 9.4 KB
  __shared__ int sbase[NBUK];                // 4.7 KB
  int tid = threadIdx.x;
  int t0 = blockIdx.x * CHUNK;
  for (int i = tid; i < NBUK; i += 256) h64[i] = 0ull;
  __syncthreads();
  int epk[16], rb[16];
#pragma unroll
  for (int i = 0; i < 16; i++) {
    int t = t0 + i * 256 + tid;
    if (t < ETOT) {
      int src, dst;
      if (t < EE) { src = ei[t]; dst = ei[EE + t]; }
      else        { src = dst = t - EE; }
      unsigned long long sa = (bitmap[src >> 5] >> (src & 31)) & 1;
      unsigned long long da = (bitmap[dst >> 5] >> (dst & 31)) & 1;
      int b = dst >> 7;
      unsigned long long ret = atomicAdd(&h64[b], 1ull | (sa << 21) | (da << 42));
      epk[i] = src | ((int)sa << 18) | ((int)da << 19) | ((dst & 127) << 20);
      rb[i] = (b << 12) | (int)(ret & 0xFFF);   // block-local rank < CHUNK=4096
    } else rb[i] = -1;
  }
  __syncthreads();
  for (int b = tid; b < NBUK; b += 256) {
    unsigned long long v = h64[b];
    sbase[b] = v ? (int)(atomicAdd(&bcnt64[b], v) & M21) : 0;
  }
  __syncthreads();
#pragma unroll
  for (int i = 0; i < 16; i++) {
    if (rb[i] >= 0) {
      int b = rb[i] >> 12;
      int r = sbase[b] + (rb[i] & 0xFFF);
      if (r < CAP) bdata[(size_t)b * CAP + r] = epk[i];
    }
  }
}

// ---------------- pass 2: fused 3-field bucket scan ----------------
__global__ void k_bscan(const unsigned long long* __restrict__ bcnt64,
    int* __restrict__ bbaseA, int* __restrict__ bbaseB,
    int* __restrict__ offsA_end, int* __restrict__ csrA, int* __restrict__ csrB){
  int lane = threadIdx.x;   // 64 threads
  int cA = 0, cB = 0;
  for (int c0 = 0; c0 < NBUK; c0 += 64) {
    int i = c0 + lane;
    unsigned long long v = (i < NBUK) ? bcnt64[i] : 0ull;
    int a = (int)((v >> 21) & M21);
    int b = (int)((v >> 42) & M21);
    int xa = a, xb = b;
#pragma unroll
    for (int d = 1; d < 64; d <<= 1) {
      int ta = __shfl_up(xa, d, 64); if (lane >= d) xa += ta;
      int tb = __shfl_up(xb, d, 64); if (lane >= d) xb += tb;
    }
    if (i < NBUK) { bbaseA[i] = cA + xa - a; bbaseB[i] = cB + xb - b; }
    cA += __shfl(xa, 63, 64);
    cB += __shfl(xb, 63, 64);
  }
  if (lane == 0) *offsA_end = cA;
  if (lane < 16) { csrA[cA + lane] = 0; csrB[cB + lane] = 0; }
}

// ---------------- pass 3: per-bucket scan + filtered scatter into csrA/csrB ----------------
__global__ __launch_bounds__(256) void k_bucket(const int* __restrict__ bdata,
    const unsigned long long* __restrict__ bcnt64,
    const int* __restrict__ bbaseA, const int* __restrict__ bbaseB,
    const int* __restrict__ flags,
    int* __restrict__ offsA, int* __restrict__ inactA,
    int* __restrict__ startB, int* __restrict__ degBv,
    int* __restrict__ csrA, int* __restrict__ csrB){
  __shared__ int deg2[128], curA[128], curB[128];   // deg2: low16=all, high16=act
  int b = blockIdx.x;
  int tid = threadIdx.x;
  int cnt = (int)(bcnt64[b] & M21);
  if (cnt > CAP) cnt = CAP;
  const int* bd = bdata + (size_t)b * CAP;
  if (tid < 128) deg2[tid] = 0;
  __syncthreads();
  for (int i = tid; i < cnt; i += 256) {
    int e = bd[i];
    int d7 = (e >> 20) & 127;
    atomicAdd(&deg2[d7], 1 + (((e >> 18) & 1) << 16));
  }
  __syncthreads();
  if (tid < 64) {
    int g0 = b * 128 + tid, g1 = g0 + 64;
    int v0 = deg2[tid], v1 = deg2[64 + tid];
    int A0 = v0 & 0xFFFF, A1 = v1 & 0xFFFF;
    int a0 = v0 >> 16,    a1 = v1 >> 16;
    int s0 = a0, s1 = a1;
#pragma unroll
    for (int d = 1; d < 64; d <<= 1) {
      int t0 = __shfl_up(s0, d, 64); if (tid >= d) s0 += t0;
      int t1 = __shfl_up(s1, d, 64); if (tid >= d) s1 += t1;
    }
    int totA0 = __shfl(s0, 63, 64);
    int eA0 = s0 - a0, eA1 = s1 - a1 + totA0;
    int baseA = bbaseA[b];
    curA[tid] = baseA + eA0; curA[64 + tid] = baseA + eA1;
    if (g0 < ND) { offsA[g0] = baseA + eA0; inactA[g0] = A0 - a0; }
    if (g1 < ND) { offsA[g1] = baseA + eA1; inactA[g1] = A1 - a1; }
    int f0 = (g0 < ND) ? flags[g0] : -1;
    int f1 = (g1 < ND) ? flags[g1] : -1;
    int w0 = (f0 >= 0) ? A0 : 0, w1 = (f1 >= 0) ? A1 : 0;
    int t0 = w0, t1 = w1;
#pragma unroll
    for (int d = 1; d < 64; d <<= 1) {
      int u0 = __shfl_up(t0, d, 64); if (tid >= d) t0 += u0;
      int u1 = __shfl_up(t1, d, 64); if (tid >= d) t1 += u1;
    }
    int totB0 = __shfl(t0, 63, 64);
    int eB0 = t0 - w0, eB1 = t1 - w1 + totB0;
    int baseB = bbaseB[b];
    curB[tid] = baseB + eB0; curB[64 + tid] = baseB + eB1;
    if (f0 >= 0) { startB[f0] = baseB + eB0; degBv[f0] = A0; }
    if (f1 >= 0) { startB[f1] = baseB + eB1; degBv[f1] = A1; }
  }
  __syncthreads();
  for (int i = tid; i < cnt; i += 256) {
    int e = bd[i];
    int d7 = (e >> 20) & 127;
    int src = e & 0x3FFFF;
    if ((e >> 19) & 1) { int p = atomicAdd(&curB[d7], 1); csrB[p] = src; }
    if ((e >> 18) & 1) {
      int ci = flags[src];
      int p = atomicAdd(&curA[d7], 1);
      csrA[p] = ci;                      // store compact idx directly
    }
  }
}

// ---------------- MFMA fp16 GEMM: C[M,N](f16) = A[M,128](f16) @ Bt[N,128]^T ----------------
template<int NT>   // N = NT*16
__global__ __launch_bounds__(256) void k_mfma(const __half* __restrict__ A,
    const __half* __restrict__ Bt, __half* __restrict__ C, int M){
  constexpr int N = NT * 16;
  int wid  = (blockIdx.x * 256 + threadIdx.x) >> 6;
  int lane = threadIdx.x & 63;
  int q = lane >> 4, mr = lane & 15;
  int r0 = wid * 32;
  if (r0 >= M) return;
  int row0 = min(r0 + mr, M - 1);
  int row1 = min(r0 + 16 + mr, M - 1);
  f4 acc[2][NT];
#pragma unroll
  for (int i = 0; i < 2; i++)
#pragma unroll
    for (int j = 0; j < NT; j++) acc[i][j] = (f4)0.f;
#pragma unroll
  for (int ks = 0; ks < 4; ks++) {
    int ko = ks * 32 + q * 8;
    h8 a0 = *(const h8*)(A + (size_t)row0 * 128 + ko);
    h8 a1 = *(const h8*)(A + (size_t)row1 * 128 + ko);
#pragma unroll
    for (int nt = 0; nt < NT; nt++) {
      h8 b = *(const h8*)(Bt + (size_t)(nt * 16 + mr) * 128 + ko);
      acc[0][nt] = __builtin_amdgcn_mfma_f32_16x16x32_f16(a0, b, acc[0][nt], 0, 0, 0);
      acc[1][nt] = __builtin_amdgcn_mfma_f32_16x16x32_f16(a1, b, acc[1][nt], 0, 0, 0);
    }
  }
#pragma unroll
  for (int mt = 0; mt < 2; mt++)
#pragma unroll
    for (int r = 0; r < 4; r++) {
      int row = r0 + mt * 16 + q * 4 + r;
      if (row < M) {
#pragma unroll
        for (int nt = 0; nt < NT; nt++)
          C[(size_t)row * N + nt * 16 + mr] = __float2half(acc[mt][nt][r]);
      }
    }
}

// ---------------- GAT layer 1 aggregation (H=2): 4 dsts per wave ----------------
// 16 lanes per dst; lane gl holds channels 8gl..8gl+7 (gl<8 -> head0, else head1).
__global__ __launch_bounds__(256) void k_agg2(const __half* __restrict__ xwc,
    const float* __restrict__ als1c, const float* __restrict__ ald1,
    const int* __restrict__ offsA, const int* __restrict__ inactA,
    const int* __restrict__ csrA,
    const float* __restrict__ bias, __half* __restrict__ out,
    const float* __restrict__ wa2s, const float* __restrict__ wa2d,
    float* __restrict__ als2, float* __restrict__ ald2, int n){
  int lane = threadIdx.x & 63;
  int gl   = lane & 15;
  int gbase = lane & 48;        // grp*16
  int w4   = (blockIdx.x * 256 + threadIdx.x) >> 6;
  int dst  = w4 * 4 + (lane >> 4);
  if (dst >= n) return;
  int e0 = offsA[dst];
  int e1 = offsA[dst + 1];
  int inact = inactA[dst];
  float2 aldv = *(const float2*)(ald1 + (size_t)dst * 2);
  bool headlo = (gl < 8);
  float den0 = 0.f, den1 = 0.f;
  float acc[8];
#pragma unroll
  for (int k = 0; k < 8; k++) acc[k] = 0.f;
  const uint4* xr = (const uint4*)xwc;     // 16 uint4 per 128-half row
  for (int base = e0; base < e1; base += 16) {
    int e = base + gl;
    bool valid = (e < e1);
    int srcv = valid ? csrA[e] : 0;
    float p0 = 0.f, p1 = 0.f;
    if (valid) {
      float2 a = *(const float2*)(als1c + (size_t)srcv * 2);
      float v0 = a.x + aldv.x, v1 = a.y + aldv.y;
      v0 = fmaxf(v0, 0.2f * v0);
      v1 = fmaxf(v1, 0.2f * v1);
      p0 = __expf(v0); p1 = __expf(v1);
    }
    den0 += p0; den1 += p1;
    int cnt = min(e1 - base, 16);
    for (int j = 0; j < cnt; j++) {
      int li = gbase + j;
      int sj = __shfl(srcv, li, 64);
      float q0 = __shfl(p0, li, 64);
      float q1 = __shfl(p1, li, 64);
      float pj = headlo ? q0 : q1;
      union { uint4 u; __half2 h[4]; } hv;
      hv.u = xr[(size_t)sj * 16 + gl];
#pragma unroll
      for (int k = 0; k < 4; k++) {
        float2 fv = __half22float2(hv.h[k]);
        acc[2*k]   = fmaf(pj, fv.x, acc[2*k]);
        acc[2*k+1] = fmaf(pj, fv.y, acc[2*k+1]);
      }
    }
  }
#pragma unroll
  for (int d = 1; d < 16; d <<= 1) {
    den0 += __shfl_xor(den0, d, 64);
    den1 += __shfl_xor(den1, d, 64);
  }
  float pin0 = __expf(fmaxf(aldv.x, 0.2f * aldv.x));
  float pin1 = __expf(fmaxf(aldv.y, 0.2f * aldv.y));
  float dt0 = den0 + (float)inact * pin0;
  float dt1 = den1 + (float)inact * pin1;
  float den = (headlo ? dt0 : dt1) + 1e-16f;
  float inv = __builtin_amdgcn_rcpf(den);
  float4 b0 = *(const float4*)(bias + 8 * gl);
  float4 b1 = *(const float4*)(bias + 8 * gl + 4);
  float v[8];
  v[0] = acc[0]*inv + b0.x; v[1] = acc[1]*inv + b0.y;
  v[2] = acc[2]*inv + b0.z; v[3] = acc[3]*inv + b0.w;
  v[4] = acc[4]*inv + b1.x; v[5] = acc[5]*inv + b1.y;
  v[6] = acc[6]*inv + b1.z; v[7] = acc[7]*inv + b1.w;
#pragma unroll
  for (int k = 0; k < 8; k++) v[k] = (v[k] > 0.f) ? v[k] : (__expf(v[k]) - 1.f);  // elu
  union { uint4 u; __half2 h[4]; } ov;
#pragma unroll
  for (int k = 0; k < 4; k++) ov.h[k] = __floats2half2_rn(v[2*k], v[2*k+1]);
  *(uint4*)(out + (size_t)dst * 128 + 8 * gl) = ov.u;
  float4 ws0 = *(const float4*)(wa2s + 8 * gl);
  float4 ws1 = *(const float4*)(wa2s + 8 * gl + 4);
  float4 wd0 = *(const float4*)(wa2d + 8 * gl);
  float4 wd1 = *(const float4*)(wa2d + 8 * gl + 4);
  float ss = v[0]*ws0.x + v[1]*ws0.y + v[2]*ws0.z + v[3]*ws0.w
           + v[4]*ws1.x + v[5]*ws1.y + v[6]*ws1.z + v[7]*ws1.w;
  float sd = v[0]*wd0.x + v[1]*wd0.y + v[2]*wd0.z + v[3]*wd0.w
           + v[4]*wd1.x + v[5]*wd1.y + v[6]*wd1.z + v[7]*wd1.w;
#pragma unroll
  for (int d = 1; d < 16; d <<= 1) {
    ss += __shfl_xor(ss, d, 64);
    sd += __shfl_xor(sd, d, 64);
  }
  if (gl == 0) { als2[dst] = ss; ald2[dst] = sd; }
}

// ---------------- gather block for layer 2 ----------------
template<int U>   // U pairs = 2U edges
__device__ __forceinline__ void gat1_blk(const int* __restrict__ cp, int j0,
    const float* __restrict__ myp, const __half2* __restrict__ xw, int cw, int hid,
    float& accx, float& accy){
  __half2 hv[U]; float pj[U];
#pragma unroll
  for (int u = 0; u < U; u++) {
    int j = j0 + 2 * u;
    int s0 = __builtin_amdgcn_readfirstlane(cp[j]);
    int s1 = __builtin_amdgcn_readfirstlane(cp[j + 1]);
    int sel = hid ? s1 : s0;
    hv[u] = xw[(size_t)sel * 32 + cw];
    pj[u] = myp[j];
  }
#pragma unroll
  for (int u = 0; u < U; u++) {
    float2 fv = __half22float2(hv[u]);
    accx = fmaf(pj[u], fv.x, accx);
    accy = fmaf(pj[u], fv.y, accy);
  }
}

// ---------------- GAT layer 2 aggregation (H=1): only active dsts ----------------
__global__ __launch_bounds__(256) void k_agg1(const __half2* __restrict__ xw2,
    const float* __restrict__ als2, const float* __restrict__ ald2,
    const int* __restrict__ startB, const int* __restrict__ degBv,
    const int* __restrict__ nodeOfC, const int* __restrict__ csrB,
    const float* __restrict__ bias, __half* __restrict__ out2c, int n){
  __shared__ float pshare[4][64];
  int c = (blockIdx.x * 256 + threadIdx.x) >> 6;
  int lane = threadIdx.x & 63;
  int ws = (threadIdx.x >> 6) & 3;
  if (c >= n) return;
  int e0  = __builtin_amdgcn_readfirstlane(startB[c]);
  int deg = __builtin_amdgcn_readfirstlane(degBv[c]);
  int e1 = e0 + deg;
  int dst = nodeOfC[c];
  float aldd = ald2[dst];
  int hid = lane >> 5;
  int cw = lane & 31;
  const float* myp = &pshare[ws][0] + hid;
  float den = 0.f, accx = 0.f, accy = 0.f;
  for (int base = e0; base < e1; base += 64) {
    int e = base + lane;
    bool valid = (e < e1);
    int srcv = valid ? csrB[e] : 0;
    float p = 0.f;
    if (valid) {
      float v = als2[srcv] + aldd;
      v = fmaxf(v, 0.2f * v);
      p = __expf(v);
    }
    den += p;
    pshare[ws][lane] = p;
    int cnt = min(e1 - base, 64);
    const int* cp = csrB + base;
    int j = 0;
    for (; j + 16 <= cnt; j += 16) gat1_blk<8>(cp, j, myp, xw2, cw, hid, accx, accy);
    if (j + 8 <= cnt) { gat1_blk<4>(cp, j, myp, xw2, cw, hid, accx, accy); j += 8; }
    if (j + 4 <= cnt) { gat1_blk<2>(cp, j, myp, xw2, cw, hid, accx, accy); j += 4; }
    for (; j < cnt; j += 2) gat1_blk<1>(cp, j, myp, xw2, cw, hid, accx, accy);
  }
  accx += __shfl_xor(accx, 32, 64);
  accy += __shfl_xor(accy, 32, 64);
  float dent = wsum64(den);
  if (lane < 32) {
    float inv = __builtin_amdgcn_rcpf(dent + 1e-16f);
    float2 b = *(const float2*)(bias + 2 * cw);
    float vx = accx * inv + b.x;
    float vy = accy * inv + b.y;
    *(__half2*)(out2c + (size_t)c * 64 + 2 * cw) = __floats2half2_rn(vx, vy);
  }
}

// ---------------- prediction head: register-tiled 64x64 GEMM, K=192 ----------------
__global__ __launch_bounds__(256) void k_head(const float* __restrict__ uemb,
    const int* __restrict__ uids,
    const __half* __restrict__ out2c, const float* __restrict__ pw1,
    const float* __restrict__ pb1, const float* __restrict__ pw2,
    const float* __restrict__ pb2, float* __restrict__ out, int B){
  __shared__ __align__(16) float As[64][196];
  __shared__ __align__(16) float Ws[192][64];
  int tid = threadIdx.x;
  for (int i = tid; i < 192 * 64 / 4; i += 256)
    ((float4*)&Ws[0][0])[i] = ((const float4*)pw1)[i];
  int w = tid >> 6, lane = tid & 63;
  int rbase = blockIdx.x * 64;
  for (int r = w; r < 64; r += 4) {
    int b = rbase + r;
    int uid = uids[b];
    As[r][lane]       = uemb[(size_t)uid * 64 + lane];
    As[r][64 + lane]  = __half2float(out2c[(size_t)(BB + b) * 64 + lane]);  // item row
    As[r][128 + lane] = __half2float(out2c[(size_t)b * 64 + lane]);        // user row
  }
  __syncthreads();
  int tm = (tid >> 4) * 4;
  int tn = (tid & 15) * 4;
  float acc[4][4];
#pragma unroll
  for (int i = 0; i < 4; i++)
#pragma unroll
    for (int j = 0; j < 4; j++) acc[i][j] = 0.f;
  for (int k = 0; k < 192; k += 4) {
    float4 a[4], wv[4];
#pragma unroll
    for (int i = 0; i < 4; i++) a[i] = *(const float4*)&As[tm + i][k];
#pragma unroll
    for (int q = 0; q < 4; q++) wv[q] = *(const float4*)&Ws[k + q][tn];
#pragma unroll
    for (int i = 0; i < 4; i++) {
      acc[i][0] = fmaf(a[i].x, wv[0].x, acc[i][0]); acc[i][1] = fmaf(a[i].x, wv[0].y, acc[i][1]);
      acc[i][2] = fmaf(a[i].x, wv[0].z, acc[i][2]); acc[i][3] = fmaf(a[i].x, wv[0].w, acc[i][3]);
      acc[i][0] = fmaf(a[i].y, wv[1].x, acc[i][0]); acc[i][1] = fmaf(a[i].y, wv[1].y, acc[i][1]);
      acc[i][2] = fmaf(a[i].y, wv[1].z, acc[i][2]); acc[i][3] = fmaf(a[i].y, wv[1].w, acc[i][3]);
      acc[i][0] = fmaf(a[i].z, wv[2].x, acc[i][0]); acc[i][1] = fmaf(a[i].z, wv[2].y, acc[i][1]);
      acc[i][2] = fmaf(a[i].z, wv[2].z, acc[i][2]); acc[i][3] = fmaf(a[i].z, wv[2].w, acc[i][3]);
      acc[i][0] = fmaf(a[i].w, wv[3].x, acc[i][0]); acc[i][1] = fmaf(a[i].w, wv[3].y, acc[i][1]);
      acc[i][2] = fmaf(a[i].w, wv[3].z, acc[i][2]); acc[i][3] = fmaf(a[i].w, wv[3].w, acc[i][3]);
    }
  }
  float4 pb1v = *(const float4*)(pb1 + tn);
  float4 pw2v = *(const float4*)(pw2 + tn);
  float pb2v = pb2[0];
#pragma unroll
  for (int i = 0; i < 4; i++) {
    float h0 = fmaxf(acc[i][0] + pb1v.x, 0.f);
    float h1 = fmaxf(acc[i][1] + pb1v.y, 0.f);
    float h2 = fmaxf(acc[i][2] + pb1v.z, 0.f);
    float h3 = fmaxf(acc[i][3] + pb1v.w, 0.f);
    float part = h0 * pw2v.x + h1 * pw2v.y + h2 * pw2v.z + h3 * pw2v.w;
#pragma unroll
    for (int d = 1; d < 16; d <<= 1) part += __shfl_xor(part, d, 64);
    if ((tid & 15) == 0) out[rbase + tm + i] = part + pb2v;
  }
}

// ---------------- launcher ----------------
extern "C" void kernel_launch(void* const* d_in, const int* in_sizes, int n_in,
                              void* d_out, int out_size, void* d_ws, size_t ws_size,
                              hipStream_t stream) {
  (void)in_sizes; (void)n_in; (void)out_size; (void)ws_size;
  const int*   user_ids = (const int*)  d_in[0];
  const int*   item_ids = (const int*)  d_in[1];
  const float* content  = (const float*)d_in[2];
  const int*   edge_idx = (const int*)  d_in[3];
  const float* uemb     = (const float*)d_in[4];
  const float* iemb     = (const float*)d_in[5];
  const float* cp_w     = (const float*)d_in[6];
  const float* cp_b     = (const float*)d_in[7];
  const float* w1       = (const float*)d_in[8];
  const float* asrc1    = (const float*)d_in[9];
  const float* adst1    = (const float*)d_in[10];
  const float* b1       = (const float*)d_in[11];
  const float* w2       = (const float*)d_in[12];
  const float* asrc2    = (const float*)d_in[13];
  const float* adst2    = (const float*)d_in[14];
  const float* b2       = (const float*)d_in[15];
  const float* pw1      = (const float*)d_in[16];
  const float* pb1      = (const float*)d_in[17];
  const float* pw2      = (const float*)d_in[18];
  const float* pb2      = (const float*)d_in[19];
  float* out = (float*)d_out;

  // ---- workspace layout (~107 MB) ----
  char* p = (char*)d_ws;
  // R0: bdata (k_bin/k_bucket) then reused as x1 (layer-1 output, full)
  int*    bdata = (int*)p;                       // [NBUK*CAP] = 19.2 MB
  __half* x1    = (__half*)p;                    // [ND,128] = 38.4 MB (after k_bucket)
  p += (size_t)ND * 128 * 2;
  __half* xc   = (__half*)p; p += (size_t)MACT * 128 * 2;   // compact input
  __half* xwc  = (__half*)p; p += (size_t)MACT * 128 * 2;   // compact xw1
  __half* xw2  = (__half*)p; p += (size_t)ND * 64 * 2;      // layer-2 xw (full)
  __half* out2c= (__half*)p; p += (size_t)MACT * 64 * 2;    // compact layer-2 out
  float* cemb  = (float*)p;  p += (size_t)BB * 64 * 4;      // content projection
  __half* Wt1  = (__half*)p; p += 16384 * 2;
  __half* Wt2  = (__half*)p; p += 8192 * 2;
  // zero region (by k_prep): [ald1 | bitmap | bcnt64]
  float* ald1     = (float*)p;
  unsigned* bitmap= (unsigned*)(ald1 + (size_t)ND * 2);
  unsigned long long* bcnt64 = (unsigned long long*)(bitmap + NBMW);
  p = (char*)(bcnt64 + NBUK);
  float* als1c = (float*)p; p += (size_t)MACT * 2 * 4;
  float* als2  = (float*)p; p += (size_t)ND * 4;
  float* ald2  = (float*)p; p += (size_t)ND * 4;
  int* flags   = (int*)p;   p += (size_t)ND * 4;            // filled 0xFF by k_prep
  int* nodeOfC = (int*)p;   p += (size_t)MACT * 4;
  int* inactA  = (int*)p;   p += (size_t)ND * 4;
  int* offsA   = (int*)p;   p += (size_t)(ND + 16) * 4;
  int* startB  = (int*)p;   p += (size_t)MACT * 4;
  int* degBv   = (int*)p;   p += (size_t)MACT * 4;
  int* bbaseA  = (int*)p;   p += NBUK * 4;
  int* bbaseB  = (int*)p;   p += NBUK * 4;
  int* csrA    = (int*)p;   p += (size_t)(ETOT + 16) * 4;
  int* csrB    = (int*)p;   p += (size_t)(ETOT + 16) * 4;
  float* wa1s  = (float*)p; p += 256 * 4;
  float* wa1d  = (float*)p; p += 256 * 4;
  float* wa2s  = (float*)p; p += 128 * 4;
  float* wa2d  = (float*)p; p += 128 * 4;

  k_prep<<<409, 256, 0, stream>>>(content, cp_w, cp_b, cemb, w1, w2, Wt1, Wt2,
                                  asrc1, adst1, asrc2, adst2,
                                  wa1s, wa1d, wa2s, wa2d,
                                  (uint4*)ald1, (uint4*)flags);

  k_scatter<<<MACT * 64 / 256, 256, 0, stream>>>(user_ids, uemb, cemb, iemb, item_ids,
      xc, wa1s, wa1d, als1c, ald1, flags, bitmap, nodeOfC);

  // CSR build: bucket sort with activity filtering
  k_bin<<<NCH, 256, 0, stream>>>(edge_idx, bitmap, bcnt64, bdata);
  k_bscan<<<1, 64, 0, stream>>>(bcnt64, bbaseA, bbaseB, offsA + ND, csrA, csrB);
  k_bucket<<<NBUK, 256, 0, stream>>>(bdata, bcnt64, bbaseA, bbaseB, flags,
                                     offsA, inactA, startB, degBv, csrA, csrB);

  // ----- GAT layer 1 (H=2): compact GEMM + filtered aggregation (4 dsts/wave) -----
  k_mfma<8><<<(MACT + 127) / 128, 256, 0, stream>>>(xc, Wt1, xwc, MACT);
  k_agg2<<<(ND * 16 + 255) / 256, 256, 0, stream>>>(xwc,
      als1c, ald1, offsA, inactA, csrA, b1, x1, wa2s, wa2d, als2, ald2, ND);

  // ----- GAT layer 2 (H=1): full GEMM + active-dst aggregation -----
  k_mfma<4><<<(ND + 127) / 128, 256, 0, stream>>>(x1, Wt2, xw2, ND);
  k_agg1<<<(MACT * 64) / 256, 256, 0, stream>>>((const __half2*)xw2, als2, ald2,
      startB, degBv, nodeOfC, csrB, b2, out2c, MACT);

  // ----- head -----
  k_head<<<BB / 64, 256, 0, stream>>>(uemb, user_ids, out2c,
                                      pw1, pb1, pw2, pb2, out, BB);
}